// Round 8
// baseline (841.070 us; speedup 1.0000x reference)
//
#include <hip/hip_runtime.h>
#include <hip/hip_bf16.h>

// GAT: 3 layers. N=50000 nodes, E=800000 edges, H=4 heads.
// R7: GEMM = m97-style 2-barrier K-loop, bf16 hi/lo split A/B.
// R8/R10/R11 (FAILED): manual gather restructures reduced in-flight loads.
// R13: elr fused into GEMM epilogue, elr2 into agg epilogue. 834.9us.
// R14 (NEUTRAL): 4 edge-offset accumulators didn't deepen the pipeline
// (VGPR 20->16, dur unchanged). Controlled comparison: aggH (identical
// address stream) runs 145us/4.35TB/s vs agg 194us/2.45TB/s. The fast
// loop's shape: ONE load -> FOUR independent FMA chains (float4 p_lds).
// R15: clone the aggH gather loop verbatim into agg/agg_bf (compute all
// 4 head accumulators, select own head at the end; 3 redundant FMAs/load
// are free at 46% VALUBusy). Wave-uniform head select.

#define NN 50000
#define NE 800000
#define NH_HEADS 4

typedef __attribute__((ext_vector_type(8))) short short8;
typedef __attribute__((ext_vector_type(4))) float floatx4;

__device__ inline float bf2f(short s) {
    union { unsigned u; float f; } v; v.u = ((unsigned)(unsigned short)s) << 16;
    return v.f;
}
__device__ inline short f2bf_rne(float x) {
    union { float f; unsigned u; } v; v.f = x;
    unsigned r = v.u + 0x7fff + ((v.u >> 16) & 1);
    return (short)(r >> 16);
}
// truncation hi/lo split: hi = trunc16(x), lo = trunc16(x - hi)
__device__ inline void split1(float x, short& h, short& l) {
    union { float f; unsigned u; } v; v.f = x;
    h = (short)(v.u >> 16);
    union { float f; unsigned u; } rv; rv.f = v.f - bf2f(h);
    l = (short)(rv.u >> 16);
}

// async 16B/lane global->LDS; lds base must be wave-uniform (dest = base + lane*16)
__device__ inline void load_lds16(const short* g, short* l) {
    __builtin_amdgcn_global_load_lds(
        (const __attribute__((address_space(1))) void*)g,
        (__attribute__((address_space(3))) void*)l, 16, 0, 0);
}

// ---------------- CSR build ----------------

__global__ void hist_kernel(const int* __restrict__ dst, int* __restrict__ deg, int E) {
    int e = blockIdx.x * 256 + threadIdx.x;
    if (e < E) atomicAdd(&deg[dst[e]], 1);
}

__global__ void scan_block_kernel(const int* __restrict__ deg, int* __restrict__ offs,
                                  int* __restrict__ bsums, int n) {
    __shared__ int s[256];
    int tid = threadIdx.x;
    int i = blockIdx.x * 256 + tid;
    int v = (i < n) ? deg[i] : 0;
    s[tid] = v;
    __syncthreads();
    for (int off = 1; off < 256; off <<= 1) {
        int x = (tid >= off) ? s[tid - off] : 0;
        __syncthreads();
        s[tid] += x;
        __syncthreads();
    }
    if (i < n) offs[i] = s[tid] - v;
    if (tid == 255) bsums[blockIdx.x] = s[255];
}

__global__ void scan_sums_kernel(const int* __restrict__ bsums, int* __restrict__ boffs, int nb) {
    __shared__ int s[256];
    int tid = threadIdx.x;
    int v = (tid < nb) ? bsums[tid] : 0;
    s[tid] = v;
    __syncthreads();
    for (int off = 1; off < 256; off <<= 1) {
        int x = (tid >= off) ? s[tid - off] : 0;
        __syncthreads();
        s[tid] += x;
        __syncthreads();
    }
    boffs[tid] = s[tid] - v;
}

__global__ void add_offs_kernel(int* __restrict__ offs, const int* __restrict__ boffs,
                                int* __restrict__ cursor, int n, int total) {
    int i = blockIdx.x * 256 + threadIdx.x;
    if (i < n) {
        int o = offs[i] + boffs[blockIdx.x];
        offs[i] = o;
        cursor[i] = o;
    }
    if (i == 0) offs[n] = total;
}

__global__ void scatter_kernel(const int* __restrict__ src, const int* __restrict__ dst,
                               int* __restrict__ cursor, int* __restrict__ psrc, int E) {
    int e = blockIdx.x * 256 + threadIdx.x;
    if (e < E) {
        int p = atomicAdd(&cursor[dst[e]], 1);
        psrc[p] = src[e];
    }
}

// ---------------- A (row-major fp32) -> row-major bf16 hi/lo ----------------

__global__ __launch_bounds__(256) void splitA_rm(const float* __restrict__ A,
                                                 short* __restrict__ hi,
                                                 short* __restrict__ lo,
                                                 int total8) {
    int tid = blockIdx.x * 256 + threadIdx.x;
    if (tid >= total8) return;
    const float* p = A + (size_t)tid * 8;
    float4 x0 = ((const float4*)p)[0];
    float4 x1 = ((const float4*)p)[1];
    float xs[8] = {x0.x, x0.y, x0.z, x0.w, x1.x, x1.y, x1.z, x1.w};
    short8 hv, lv;
#pragma unroll
    for (int j = 0; j < 8; ++j) { short h, l; split1(xs[j], h, l); hv[j] = h; lv[j] = l; }
    ((short8*)hi)[tid] = hv;
    ((short8*)lo)[tid] = lv;
}

// ---------------- B -> bf16 hi/lo in MFMA B-fragment order ----------------
// offset (short8) = (c*(N/16)+g)*64 + lane ; lane=(n&15)+16*((k&31)>>3), j=k&7

__global__ __launch_bounds__(256) void splitB_kernel(const float* __restrict__ B,
                                                     short* __restrict__ hi,
                                                     short* __restrict__ lo,
                                                     int K, int N) {
    int tid = blockIdx.x * 256 + threadIdx.x;
    int NG = N >> 4;
    int total = (K >> 5) * NG * 64;
    if (tid >= total) return;
    int lane = tid & 63;
    int rc = tid >> 6;
    int g = rc % NG, c = rc / NG;
    int n = g * 16 + (lane & 15);
    int k = c * 32 + (lane >> 4) * 8;
    short8 hv, lv;
#pragma unroll
    for (int j = 0; j < 8; ++j) {
        float x = B[(size_t)(k + j) * N + n];
        short h = f2bf_rne(x);
        hv[j] = h;
        lv[j] = f2bf_rne(x - bf2f(h));
    }
    ((short8*)hi)[tid] = hv;
    ((short8*)lo)[tid] = lv;
}

// permuted-W2: Bp[h*256+k, c] = W2[k, h*256+c]; K=1024, N=256
__global__ __launch_bounds__(256) void splitB2_kernel(const float* __restrict__ W2,
                                                      short* __restrict__ hi,
                                                      short* __restrict__ lo) {
    int tid = blockIdx.x * 256 + threadIdx.x;
    const int NG = 16;
    int total = (1024 >> 5) * NG * 64;   // 32768
    if (tid >= total) return;
    int lane = tid & 63;
    int rc = tid >> 6;
    int g = rc % NG, c = rc / NG;
    int n = g * 16 + (lane & 15);
    int kk = c * 32 + (lane >> 4) * 8;
    short8 hv, lv;
#pragma unroll
    for (int j = 0; j < 8; ++j) {
        int kg = kk + j;
        int h = kg >> 8, k = kg & 255;
        float x = W2[(size_t)k * 1024 + h * 256 + n];
        short hb = f2bf_rne(x);
        hv[j] = hb;
        lv[j] = f2bf_rne(x - bf2f(hb));
    }
    ((short8*)hi)[tid] = hv;
    ((short8*)lo)[tid] = lv;
}

// ---------------- MFMA GEMM, N=256, A via async LDS staging ----------------
// block: 64 rows x 256 cols; wave w owns rows [bm,bm+64) x cols [w*64,(w+1)*64).
// Optional fused elr epilogue (alv!=null): wave w = head w computes
// el[n,w] = z[n, w*64..w*64+64) . alv[w], er likewise, via 4 FMA +
// 4-step shfl_xor reduce over the 16-lane col group per row.

__device__ inline floatx4 mfma16(short8 a, short8 b, floatx4 c) {
    return __builtin_amdgcn_mfma_f32_16x16x32_bf16(a, b, c, 0, 0, 0);
}

__global__ __launch_bounds__(256) void gemm_n256l(const short* __restrict__ Ahi,
                                                  const short* __restrict__ Alo,
                                                  const short* __restrict__ Bh,
                                                  const short* __restrict__ Bl,
                                                  const float* __restrict__ bias4,
                                                  float* __restrict__ C,
                                                  const float* __restrict__ alv,
                                                  const float* __restrict__ arv,
                                                  float* __restrict__ elo,
                                                  float* __restrict__ ero,
                                                  int M, int K) {
    int KC = K >> 5;
    __shared__ short AhL[2048];   // 4 m-tiles x 64 lanes x 8 shorts = 4 KB
    __shared__ short AlL[2048];
    int t = threadIdx.x;
    int lane = t & 63;
    int w = t >> 6;
    int bm = blockIdx.x * 64;
    int g0 = w * 4;
    const short8* pBh = (const short8*)Bh;
    const short8* pBl = (const short8*)Bl;

    floatx4 acc[4][4] = {};

    // staging source for this lane (m-tile w)
    int row = bm + (w << 4) + (lane & 15);
    if (row >= M) row = M - 1;                    // clamp: junk rows never stored
    const short* gh = Ahi + (size_t)row * K + ((lane >> 4) << 3);
    const short* gl = Alo + (size_t)row * K + ((lane >> 4) << 3);
    short* lh = AhL + w * 512;                    // wave-uniform LDS base
    short* ll = AlL + w * 512;

    for (int c = 0; c < KC; ++c) {
        load_lds16(gh + (size_t)c * 32, lh);
        load_lds16(gl + (size_t)c * 32, ll);
        short8 bh[4], bl[4];
#pragma unroll
        for (int g = 0; g < 4; ++g) {
            bh[g] = pBh[((size_t)c * (256 / 16) + g0 + g) * 64 + lane];
            bl[g] = pBl[((size_t)c * (256 / 16) + g0 + g) * 64 + lane];
        }
        __syncthreads();   // drains vmcnt: LDS staged, B regs ready
#pragma unroll
        for (int mt = 0; mt < 4; ++mt) {
            short8 ah = *(const short8*)(AhL + mt * 512 + lane * 8);
            short8 al = *(const short8*)(AlL + mt * 512 + lane * 8);
#pragma unroll
            for (int g = 0; g < 4; ++g) {
                acc[mt][g] = mfma16(ah, bh[g], acc[mt][g]);
                acc[mt][g] = mfma16(al, bh[g], acc[mt][g]);
                acc[mt][g] = mfma16(ah, bl[g], acc[mt][g]);
            }
        }
        __syncthreads();   // all LDS reads done before next overwrite
    }

    // C/D layout: col = lane&15, row = (lane>>4)*4 + reg
    int rowb = bm + (lane >> 4) * 4;
    int colb = w * 64 + (lane & 15);
#pragma unroll
    for (int mt = 0; mt < 4; ++mt) {
#pragma unroll
        for (int r = 0; r < 4; ++r) {
            int rr = rowb + mt * 16 + r;
            if (rr < M) {
#pragma unroll
                for (int g = 0; g < 4; ++g) {
                    int col = colb + g * 16;
                    float v = acc[mt][g][r];
                    if (bias4) {
                        v = 0.25f * (v + bias4[col] + bias4[col + 256] +
                                     bias4[col + 512] + bias4[col + 768]);
                    }
                    C[(size_t)rr * 256 + col] = v;
                }
            }
        }
    }

    // fused elr: el[rr,w] = sum_f z[rr, w*64+f]*alv[w*64+f] (f = (lane&15)+g*16)
    if (alv) {
        float alr[4], arr_[4];
#pragma unroll
        for (int g = 0; g < 4; ++g) {
            int f = w * 64 + (lane & 15) + g * 16;
            alr[g] = alv[f];
            arr_[g] = arv[f];
        }
#pragma unroll
        for (int mt = 0; mt < 4; ++mt) {
#pragma unroll
            for (int r = 0; r < 4; ++r) {
                float se = acc[mt][0][r] * alr[0] + acc[mt][1][r] * alr[1] +
                           acc[mt][2][r] * alr[2] + acc[mt][3][r] * alr[3];
                float sr = acc[mt][0][r] * arr_[0] + acc[mt][1][r] * arr_[1] +
                           acc[mt][2][r] * arr_[2] + acc[mt][3][r] * arr_[3];
                se += __shfl_xor(se, 1); se += __shfl_xor(se, 2);
                se += __shfl_xor(se, 4); se += __shfl_xor(se, 8);
                sr += __shfl_xor(sr, 1); sr += __shfl_xor(sr, 2);
                sr += __shfl_xor(sr, 4); sr += __shfl_xor(sr, 8);
                int rr = rowb + mt * 16 + r;
                if ((lane & 15) == 0 && rr < M) {
                    elo[rr * 4 + w] = se;
                    ero[rr * 4 + w] = sr;
                }
            }
        }
    }
}

// ---------------- attention score parts (layer 2) ----------------

// val[h*256+k] = sum_j W2[k,h*256+j]*al2[h,j] ; var likewise with ar2
__global__ __launch_bounds__(256) void proj_av_kernel(const float* __restrict__ W2,
                                                      const float* __restrict__ al2,
                                                      const float* __restrict__ ar2,
                                                      float* __restrict__ val,
                                                      float* __restrict__ var_) {
    int gid = blockIdx.x * 256 + threadIdx.x;
    int w = gid >> 6;
    int lane = threadIdx.x & 63;
    if (w >= 1024) return;
    int h = w >> 8, k = w & 255;
    const float* wrow = W2 + (size_t)k * 1024 + h * 256;
    const float* ap = al2 + h * 256;
    const float* rp = ar2 + h * 256;
    float sv = 0.f, sr = 0.f;
    for (int j = lane; j < 256; j += 64) {
        float x = wrow[j];
        sv += x * ap[j];
        sr += x * rp[j];
    }
#pragma unroll
    for (int off = 32; off > 0; off >>= 1) {
        sv += __shfl_down(sv, off);
        sr += __shfl_down(sr, off);
    }
    if (lane == 0) { val[w] = sv; var_[w] = sr; }
}

// el[n,h] = h1[n,:]·val[h,:], er likewise  (fallback when ws too small to fuse)
__global__ __launch_bounds__(256) void elr2_kernel(const float* __restrict__ h1,
                                                   const float* __restrict__ val,
                                                   const float* __restrict__ var_,
                                                   float* __restrict__ el,
                                                   float* __restrict__ er) {
    int gid = blockIdx.x * 256 + threadIdx.x;
    int w = gid >> 6;
    int lane = threadIdx.x & 63;
    if (w >= NN * 4) return;
    int n = w >> 2, h = w & 3;
    const float* hr = h1 + (size_t)n * 256;
    const float* vp = val + h * 256;
    const float* rp = var_ + h * 256;
    float se = 0.f, sr = 0.f;
    for (int k = lane; k < 256; k += 64) {
        float x = hr[k];
        se += x * vp[k];
        sr += x * rp[k];
    }
#pragma unroll
    for (int off = 32; off > 0; off >>= 1) {
        se += __shfl_down(se, off);
        sr += __shfl_down(sr, off);
    }
    if (lane == 0) { el[w] = se; er[w] = sr; }
}

// ---------------- aggregation ----------------
// All gather loops use the aggH shape (measured 4.35TB/s): one loaded value
// feeds 4 independent FMA chains (contiguous float4 p_lds read). agg/agg_bf
// select their wave-uniform head at the end (3 redundant FMAs/load are free
// at 46% VALUBusy).

// layer 0: elu epilogue, writes bf16 hi/lo row-major (consumed only by L1 GEMM)

__global__ __launch_bounds__(256) void agg_bf_kernel(const float* __restrict__ z,
                                                     const float* __restrict__ el,
                                                     const float* __restrict__ er,
                                                     const int* __restrict__ offs,
                                                     const int* __restrict__ psrc,
                                                     const float* __restrict__ bias,
                                                     short* __restrict__ ohi,
                                                     short* __restrict__ olo) {
    int n = blockIdx.x;
    int t = threadIdx.x;
    int h = t >> 6;
    __shared__ float p_lds[64][4];
    __shared__ int src_lds[64];
    __shared__ float den_lds[4];
    if (t < 4) den_lds[t] = 0.f;
    int beg = offs[n], end = offs[n + 1];
    float a0 = 0.f, a1 = 0.f, a2 = 0.f, a3 = 0.f;
    int e_local = t >> 2, hh = t & 3;
    float er_n = er[n * 4 + hh];
    for (int base = beg; base < end; base += 64) {
        int cnt = min(64, end - base);
        __syncthreads();
        if (e_local < cnt) {
            int s = psrc[base + e_local];
            if (hh == 0) src_lds[e_local] = s;
            float sc = el[s * 4 + hh] + er_n;
            sc = (sc > 0.f) ? sc : 0.2f * sc;
            float p = __expf(sc);
            p_lds[e_local][hh] = p;
            atomicAdd(&den_lds[hh], p);
        }
        __syncthreads();
        for (int e = 0; e < cnt; ++e) {
            float v = z[(size_t)src_lds[e] * 256 + t];
            a0 += p_lds[e][0] * v;
            a1 += p_lds[e][1] * v;
            a2 += p_lds[e][2] * v;
            a3 += p_lds[e][3] * v;
        }
    }
    __syncthreads();
    float acc = (h == 0) ? a0 : (h == 1) ? a1 : (h == 2) ? a2 : a3;  // wave-uniform
    float o = acc / fmaxf(den_lds[h], 1e-9f) + bias[t];
    o = (o > 0.f) ? o : (__expf(o) - 1.f);
    short hv, lv;
    split1(o, hv, lv);
    ohi[(size_t)n * 256 + t] = hv;
    olo[(size_t)n * 256 + t] = lv;
}

// layer 1: elu epilogue, fp32 out (consumed by aggH gathers). Optionally fuses
// elr2: el2[n,h] = out[n,:]·val[h,:], er2 likewise (val!=nullptr => fused).

__global__ __launch_bounds__(256) void agg_kernel(const float* __restrict__ z,
                                                  const float* __restrict__ el,
                                                  const float* __restrict__ er,
                                                  const int* __restrict__ offs,
                                                  const int* __restrict__ psrc,
                                                  const float* __restrict__ bias,
                                                  float* __restrict__ out,
                                                  const float* __restrict__ val,
                                                  const float* __restrict__ var_,
                                                  float* __restrict__ el2,
                                                  float* __restrict__ er2) {
    int n = blockIdx.x;
    int t = threadIdx.x;
    int h = t >> 6;
    __shared__ float p_lds[64][4];
    __shared__ int src_lds[64];
    __shared__ float den_lds[4];
    __shared__ float red[4][8];
    if (t < 4) den_lds[t] = 0.f;
    int beg = offs[n], end = offs[n + 1];
    float a0 = 0.f, a1 = 0.f, a2 = 0.f, a3 = 0.f;
    int e_local = t >> 2, hh = t & 3;
    float er_n = er[n * 4 + hh];
    for (int base = beg; base < end; base += 64) {
        int cnt = min(64, end - base);
        __syncthreads();
        if (e_local < cnt) {
            int s = psrc[base + e_local];
            if (hh == 0) src_lds[e_local] = s;
            float sc = el[s * 4 + hh] + er_n;
            sc = (sc > 0.f) ? sc : 0.2f * sc;
            float p = __expf(sc);
            p_lds[e_local][hh] = p;
            atomicAdd(&den_lds[hh], p);
        }
        __syncthreads();
        for (int e = 0; e < cnt; ++e) {
            float v = z[(size_t)src_lds[e] * 256 + t];
            a0 += p_lds[e][0] * v;
            a1 += p_lds[e][1] * v;
            a2 += p_lds[e][2] * v;
            a3 += p_lds[e][3] * v;
        }
    }
    __syncthreads();
    float acc = (h == 0) ? a0 : (h == 1) ? a1 : (h == 2) ? a2 : a3;  // wave-uniform
    float o = acc / fmaxf(den_lds[h], 1e-9f) + bias[t];
    o = (o > 0.f) ? o : (__expf(o) - 1.f);
    out[(size_t)n * 256 + t] = o;
    if (val) {
        // fused elr2: block-wide dot of o with val/var_ rows (k = t)
        float s0 = o * val[t],        s1 = o * val[256 + t];
        float s2 = o * val[512 + t],  s3 = o * val[768 + t];
        float r0 = o * var_[t],       r1 = o * var_[256 + t];
        float r2 = o * var_[512 + t], r3 = o * var_[768 + t];
#pragma unroll
        for (int off = 32; off > 0; off >>= 1) {
            s0 += __shfl_down(s0, off); s1 += __shfl_down(s1, off);
            s2 += __shfl_down(s2, off); s3 += __shfl_down(s3, off);
            r0 += __shfl_down(r0, off); r1 += __shfl_down(r1, off);
            r2 += __shfl_down(r2, off); r3 += __shfl_down(r3, off);
        }
        int lane = t & 63;
        if (lane == 0) {
            red[h][0] = s0; red[h][1] = s1; red[h][2] = s2; red[h][3] = s3;
            red[h][4] = r0; red[h][5] = r1; red[h][6] = r2; red[h][7] = r3;
        }
        __syncthreads();
        if (t < 8) {
            float sum = red[0][t] + red[1][t] + red[2][t] + red[3][t];
            if (t < 4) el2[n * 4 + t] = sum;
            else       er2[n * 4 + (t - 4)] = sum;
        }
    }
}

// layer-2 aggregation of h1 -> bf16 hi/lo row-major [N,1024] (consumed only by fin GEMM)

__global__ __launch_bounds__(256) void aggH_bf_kernel(const float* __restrict__ h1,
                                                      const float* __restrict__ el,
                                                      const float* __restrict__ er,
                                                      const int* __restrict__ offs,
                                                      const int* __restrict__ psrc,
                                                      short* __restrict__ ohi,
                                                      short* __restrict__ olo) {
    int n = blockIdx.x, t = threadIdx.x;
    __shared__ float p_lds[64][4];
    __shared__ int src_lds[64];
    __shared__ float den_lds[4];
    if (t < 4) den_lds[t] = 0.f;
    int beg = offs[n], end = offs[n + 1];
    float a0 = 0.f, a1 = 0.f, a2 = 0.f, a3 = 0.f;
    int e_local = t >> 2, hh = t & 3;
    float er_n = er[n * 4 + hh];
    for (int base = beg; base < end; base += 64) {
        int cnt = min(64, end - base);
        __syncthreads();
        if (e_local < cnt) {
            int s = psrc[base + e_local];
            if (hh == 0) src_lds[e_local] = s;
            float sc = el[s * 4 + hh] + er_n;
            sc = (sc > 0.f) ? sc : 0.2f * sc;
            float p = __expf(sc);
            p_lds[e_local][hh] = p;
            atomicAdd(&den_lds[hh], p);
        }
        __syncthreads();
        for (int e = 0; e < cnt; ++e) {
            float v = h1[(size_t)src_lds[e] * 256 + t];
            a0 += p_lds[e][0] * v;
            a1 += p_lds[e][1] * v;
            a2 += p_lds[e][2] * v;
            a3 += p_lds[e][3] * v;
        }
    }
    __syncthreads();
    float vals[4];
    vals[0] = a0 / fmaxf(den_lds[0], 1e-9f);
    vals[1] = a1 / fmaxf(den_lds[1], 1e-9f);
    vals[2] = a2 / fmaxf(den_lds[2], 1e-9f);
    vals[3] = a3 / fmaxf(den_lds[3], 1e-9f);
    size_t base_o = (size_t)n * 1024 + t;
#pragma unroll
    for (int h = 0; h < 4; ++h) {
        short hv, lv;
        split1(vals[h], hv, lv);
        ohi[base_o + h * 256] = hv;
        olo[base_o + h * 256] = lv;
    }
}

// ---------------- launch ----------------

extern "C" void kernel_launch(void* const* d_in, const int* in_sizes, int n_in,
                              void* d_out, int out_size, void* d_ws, size_t ws_size,
                              hipStream_t stream) {
    const float* feat = (const float*)d_in[0];
    const float* W0 = (const float*)d_in[1];
    const float* al0 = (const float*)d_in[2];
    const float* ar0 = (const float*)d_in[3];
    const float* b0 = (const float*)d_in[4];
    const float* W1 = (const float*)d_in[5];
    const float* al1 = (const float*)d_in[6];
    const float* ar1 = (const float*)d_in[7];
    const float* b1 = (const float*)d_in[8];
    const float* W2 = (const float*)d_in[9];
    const float* al2 = (const float*)d_in[10];
    const float* ar2 = (const float*)d_in[11];
    const float* b2 = (const float*)d_in[12];
    const int* src = (const int*)d_in[13];
    const int* dst = (const int*)d_in[14];
    float* out = (float*)d_out;

    // ---- workspace layout (~262.5 MB + optional 1.6 MB), time-multiplexed ----
    float* slotA = (float*)d_ws;
    float* z = slotA;                                     // [N,256] fp32
    short* feathi = (short*)(slotA + (size_t)NN * 256);   // 50000*128 shorts
    short* featlo = feathi + (size_t)NN * 128;
    short* Ahi = (short*)slotA;                           // [N,1024] shorts (layer 2)
    short* Alo = Ahi + (size_t)NN * 1024;
    float* slotB = slotA + (size_t)NN * 1024;
    short* h0hi = (short*)slotB;                          // 50000*256 shorts
    short* h0lo = h0hi + (size_t)NN * 256;
    float* h1 = slotB;                                    // [N,256] fp32 (layer 2)
    float* el = slotB + (size_t)NN * 256;                 // 200000
    float* er = el + (size_t)NN * NH_HEADS;               // 200000
    int* deg = (int*)(er + (size_t)NN * NH_HEADS);        // 50000
    int* offs = deg + NN;                                 // 50001 (+1 pad)
    int* cursor = offs + NN + 2;                          // 50000
    int* bsums = cursor + NN;                             // 256
    int* boffs = bsums + 256;                             // 256
    int* psrc = boffs + 256;                              // 800000 (+2 pad)
    short* Bh = (short*)(psrc + NE + 2);                  // 262144 shorts
    short* Bl = Bh + 262144;                              // 262144 shorts
    float* val = (float*)(Bl + 262144);                   // 1024
    float* var_ = val + 1024;                             // 1024
    // separate layer-2 score buffers (el/er stay live during agg_kernel's
    // gather phase, so the fused epilogue must not write over them)
    float* el2 = var_ + 1024;                             // 200000
    float* er2 = el2 + (size_t)NN * NH_HEADS;             // 200000
    size_t need = (size_t)((char*)(er2 + (size_t)NN * NH_HEADS) - (char*)d_ws);
    bool fuse_elr2 = need <= ws_size;

    // ---- CSR build (by dst) ----
    hipMemsetAsync(deg, 0, NN * sizeof(int), stream);
    hist_kernel<<<(NE + 255) / 256, 256, 0, stream>>>(dst, deg, NE);
    int nb = (NN + 255) / 256;
    scan_block_kernel<<<nb, 256, 0, stream>>>(deg, offs, bsums, NN);
    scan_sums_kernel<<<1, 256, 0, stream>>>(bsums, boffs, nb);
    add_offs_kernel<<<nb, 256, 0, stream>>>(offs, boffs, cursor, NN, NE);
    scatter_kernel<<<(NE + 255) / 256, 256, 0, stream>>>(src, dst, cursor, psrc, NE);

    int mb64 = (NN + 63) / 64; // 782

    // ---- layer 0: 128 -> 4x64, elu (elr fused into GEMM epilogue) ----
    splitA_rm<<<(NN * 128 / 8 + 255) / 256, 256, 0, stream>>>(feat, feathi, featlo, NN * 128 / 8);
    splitB_kernel<<<(4096 + 255) / 256, 256, 0, stream>>>(W0, Bh, Bl, 128, 256);
    gemm_n256l<<<mb64, 256, 0, stream>>>(feathi, featlo, Bh, Bl, nullptr, z,
                                         al0, ar0, el, er, NN, 128);
    agg_bf_kernel<<<NN, 256, 0, stream>>>(z, el, er, offs, psrc, b0, h0hi, h0lo);

    // ---- layer 1: 256 -> 4x64, elu (elr fused; elr2 fused into agg) ----
    splitB_kernel<<<(8192 + 255) / 256, 256, 0, stream>>>(W1, Bh, Bl, 256, 256);
    gemm_n256l<<<mb64, 256, 0, stream>>>(h0hi, h0lo, Bh, Bl, nullptr, z,
                                         al1, ar1, el, er, NN, 256);
    proj_av_kernel<<<256, 256, 0, stream>>>(W2, al2, ar2, val, var_);
    agg_kernel<<<NN, 256, 0, stream>>>(z, el, er, offs, psrc, b1, h1,
                                       fuse_elr2 ? val : nullptr, var_, el2, er2);

    // ---- layer 2 (restructured): aggregate h1, then project ----
    const float* elF;
    const float* erF;
    if (fuse_elr2) {
        elF = el2; erF = er2;
    } else {
        elr2_kernel<<<NN, 256, 0, stream>>>(h1, val, var_, el, er);
        elF = el; erF = er;
    }
    aggH_bf_kernel<<<NN, 256, 0, stream>>>(h1, elF, erF, offs, psrc, Ahi, Alo);
    splitB2_kernel<<<(32768 + 255) / 256, 256, 0, stream>>>(W2, Bh, Bl);
    gemm_n256l<<<mb64, 256, 0, stream>>>(Ahi, Alo, Bh, Bl, b2, out,
                                         nullptr, nullptr, nullptr, nullptr, NN, 1024);
}

// Round 9
// 828.280 us; speedup vs baseline: 1.0154x; 1.0154x over previous
//
#include <hip/hip_runtime.h>
#include <hip/hip_bf16.h>

// GAT: 3 layers. N=50000 nodes, E=800000 edges, H=4 heads.
// R7: GEMM = m97-style 2-barrier K-loop, bf16 hi/lo split A/B.
// R8/R10/R11 (FAILED): manual gather restructures reduced in-flight loads.
// R13: elr fused into GEMM epilogue (kept: worth ~27us). 834.9us.
// R14/R15 (NEUTRAL/HURT): edge-unroll and aggH-clone loops didn't fix agg.
// R16: the controlled pair R0-vs-R6 (same loop, +/-fused elr2) shows the
// FUSED ELR2 EPILOGUE costs ~50us in agg_kernel (every fused variant
// 175-204us across 4 different loops; the only sub-145 agg had none).
// Unfuse: separate elr2_kernel (~13us). agg/agg_bf reverted to byte-exact
// R0 bodies (the only form ever measured <145us). aggH untouched.

#define NN 50000
#define NE 800000
#define NH_HEADS 4

typedef __attribute__((ext_vector_type(8))) short short8;
typedef __attribute__((ext_vector_type(4))) float floatx4;

__device__ inline float bf2f(short s) {
    union { unsigned u; float f; } v; v.u = ((unsigned)(unsigned short)s) << 16;
    return v.f;
}
__device__ inline short f2bf_rne(float x) {
    union { float f; unsigned u; } v; v.f = x;
    unsigned r = v.u + 0x7fff + ((v.u >> 16) & 1);
    return (short)(r >> 16);
}
// truncation hi/lo split: hi = trunc16(x), lo = trunc16(x - hi)
__device__ inline void split1(float x, short& h, short& l) {
    union { float f; unsigned u; } v; v.f = x;
    h = (short)(v.u >> 16);
    union { float f; unsigned u; } rv; rv.f = v.f - bf2f(h);
    l = (short)(rv.u >> 16);
}

// async 16B/lane global->LDS; lds base must be wave-uniform (dest = base + lane*16)
__device__ inline void load_lds16(const short* g, short* l) {
    __builtin_amdgcn_global_load_lds(
        (const __attribute__((address_space(1))) void*)g,
        (__attribute__((address_space(3))) void*)l, 16, 0, 0);
}

// ---------------- CSR build ----------------

__global__ void hist_kernel(const int* __restrict__ dst, int* __restrict__ deg, int E) {
    int e = blockIdx.x * 256 + threadIdx.x;
    if (e < E) atomicAdd(&deg[dst[e]], 1);
}

__global__ void scan_block_kernel(const int* __restrict__ deg, int* __restrict__ offs,
                                  int* __restrict__ bsums, int n) {
    __shared__ int s[256];
    int tid = threadIdx.x;
    int i = blockIdx.x * 256 + tid;
    int v = (i < n) ? deg[i] : 0;
    s[tid] = v;
    __syncthreads();
    for (int off = 1; off < 256; off <<= 1) {
        int x = (tid >= off) ? s[tid - off] : 0;
        __syncthreads();
        s[tid] += x;
        __syncthreads();
    }
    if (i < n) offs[i] = s[tid] - v;
    if (tid == 255) bsums[blockIdx.x] = s[255];
}

__global__ void scan_sums_kernel(const int* __restrict__ bsums, int* __restrict__ boffs, int nb) {
    __shared__ int s[256];
    int tid = threadIdx.x;
    int v = (tid < nb) ? bsums[tid] : 0;
    s[tid] = v;
    __syncthreads();
    for (int off = 1; off < 256; off <<= 1) {
        int x = (tid >= off) ? s[tid - off] : 0;
        __syncthreads();
        s[tid] += x;
        __syncthreads();
    }
    boffs[tid] = s[tid] - v;
}

__global__ void add_offs_kernel(int* __restrict__ offs, const int* __restrict__ boffs,
                                int* __restrict__ cursor, int n, int total) {
    int i = blockIdx.x * 256 + threadIdx.x;
    if (i < n) {
        int o = offs[i] + boffs[blockIdx.x];
        offs[i] = o;
        cursor[i] = o;
    }
    if (i == 0) offs[n] = total;
}

__global__ void scatter_kernel(const int* __restrict__ src, const int* __restrict__ dst,
                               int* __restrict__ cursor, int* __restrict__ psrc, int E) {
    int e = blockIdx.x * 256 + threadIdx.x;
    if (e < E) {
        int p = atomicAdd(&cursor[dst[e]], 1);
        psrc[p] = src[e];
    }
}

// ---------------- A (row-major fp32) -> row-major bf16 hi/lo ----------------

__global__ __launch_bounds__(256) void splitA_rm(const float* __restrict__ A,
                                                 short* __restrict__ hi,
                                                 short* __restrict__ lo,
                                                 int total8) {
    int tid = blockIdx.x * 256 + threadIdx.x;
    if (tid >= total8) return;
    const float* p = A + (size_t)tid * 8;
    float4 x0 = ((const float4*)p)[0];
    float4 x1 = ((const float4*)p)[1];
    float xs[8] = {x0.x, x0.y, x0.z, x0.w, x1.x, x1.y, x1.z, x1.w};
    short8 hv, lv;
#pragma unroll
    for (int j = 0; j < 8; ++j) { short h, l; split1(xs[j], h, l); hv[j] = h; lv[j] = l; }
    ((short8*)hi)[tid] = hv;
    ((short8*)lo)[tid] = lv;
}

// ---------------- B -> bf16 hi/lo in MFMA B-fragment order ----------------
// offset (short8) = (c*(N/16)+g)*64 + lane ; lane=(n&15)+16*((k&31)>>3), j=k&7

__global__ __launch_bounds__(256) void splitB_kernel(const float* __restrict__ B,
                                                     short* __restrict__ hi,
                                                     short* __restrict__ lo,
                                                     int K, int N) {
    int tid = blockIdx.x * 256 + threadIdx.x;
    int NG = N >> 4;
    int total = (K >> 5) * NG * 64;
    if (tid >= total) return;
    int lane = tid & 63;
    int rc = tid >> 6;
    int g = rc % NG, c = rc / NG;
    int n = g * 16 + (lane & 15);
    int k = c * 32 + (lane >> 4) * 8;
    short8 hv, lv;
#pragma unroll
    for (int j = 0; j < 8; ++j) {
        float x = B[(size_t)(k + j) * N + n];
        short h = f2bf_rne(x);
        hv[j] = h;
        lv[j] = f2bf_rne(x - bf2f(h));
    }
    ((short8*)hi)[tid] = hv;
    ((short8*)lo)[tid] = lv;
}

// permuted-W2: Bp[h*256+k, c] = W2[k, h*256+c]; K=1024, N=256
__global__ __launch_bounds__(256) void splitB2_kernel(const float* __restrict__ W2,
                                                      short* __restrict__ hi,
                                                      short* __restrict__ lo) {
    int tid = blockIdx.x * 256 + threadIdx.x;
    const int NG = 16;
    int total = (1024 >> 5) * NG * 64;   // 32768
    if (tid >= total) return;
    int lane = tid & 63;
    int rc = tid >> 6;
    int g = rc % NG, c = rc / NG;
    int n = g * 16 + (lane & 15);
    int kk = c * 32 + (lane >> 4) * 8;
    short8 hv, lv;
#pragma unroll
    for (int j = 0; j < 8; ++j) {
        int kg = kk + j;
        int h = kg >> 8, k = kg & 255;
        float x = W2[(size_t)k * 1024 + h * 256 + n];
        short hb = f2bf_rne(x);
        hv[j] = hb;
        lv[j] = f2bf_rne(x - bf2f(hb));
    }
    ((short8*)hi)[tid] = hv;
    ((short8*)lo)[tid] = lv;
}

// ---------------- MFMA GEMM, N=256, A via async LDS staging ----------------
// block: 64 rows x 256 cols; wave w owns rows [bm,bm+64) x cols [w*64,(w+1)*64).
// Optional fused elr epilogue (alv!=null): wave w = head w computes
// el[n,w] = z[n, w*64..w*64+64) . alv[w], er likewise, via 4 FMA +
// 4-step shfl_xor reduce over the 16-lane col group per row.

__device__ inline floatx4 mfma16(short8 a, short8 b, floatx4 c) {
    return __builtin_amdgcn_mfma_f32_16x16x32_bf16(a, b, c, 0, 0, 0);
}

__global__ __launch_bounds__(256) void gemm_n256l(const short* __restrict__ Ahi,
                                                  const short* __restrict__ Alo,
                                                  const short* __restrict__ Bh,
                                                  const short* __restrict__ Bl,
                                                  const float* __restrict__ bias4,
                                                  float* __restrict__ C,
                                                  const float* __restrict__ alv,
                                                  const float* __restrict__ arv,
                                                  float* __restrict__ elo,
                                                  float* __restrict__ ero,
                                                  int M, int K) {
    int KC = K >> 5;
    __shared__ short AhL[2048];   // 4 m-tiles x 64 lanes x 8 shorts = 4 KB
    __shared__ short AlL[2048];
    int t = threadIdx.x;
    int lane = t & 63;
    int w = t >> 6;
    int bm = blockIdx.x * 64;
    int g0 = w * 4;
    const short8* pBh = (const short8*)Bh;
    const short8* pBl = (const short8*)Bl;

    floatx4 acc[4][4] = {};

    // staging source for this lane (m-tile w)
    int row = bm + (w << 4) + (lane & 15);
    if (row >= M) row = M - 1;                    // clamp: junk rows never stored
    const short* gh = Ahi + (size_t)row * K + ((lane >> 4) << 3);
    const short* gl = Alo + (size_t)row * K + ((lane >> 4) << 3);
    short* lh = AhL + w * 512;                    // wave-uniform LDS base
    short* ll = AlL + w * 512;

    for (int c = 0; c < KC; ++c) {
        load_lds16(gh + (size_t)c * 32, lh);
        load_lds16(gl + (size_t)c * 32, ll);
        short8 bh[4], bl[4];
#pragma unroll
        for (int g = 0; g < 4; ++g) {
            bh[g] = pBh[((size_t)c * (256 / 16) + g0 + g) * 64 + lane];
            bl[g] = pBl[((size_t)c * (256 / 16) + g0 + g) * 64 + lane];
        }
        __syncthreads();   // drains vmcnt: LDS staged, B regs ready
#pragma unroll
        for (int mt = 0; mt < 4; ++mt) {
            short8 ah = *(const short8*)(AhL + mt * 512 + lane * 8);
            short8 al = *(const short8*)(AlL + mt * 512 + lane * 8);
#pragma unroll
            for (int g = 0; g < 4; ++g) {
                acc[mt][g] = mfma16(ah, bh[g], acc[mt][g]);
                acc[mt][g] = mfma16(al, bh[g], acc[mt][g]);
                acc[mt][g] = mfma16(ah, bl[g], acc[mt][g]);
            }
        }
        __syncthreads();   // all LDS reads done before next overwrite
    }

    // C/D layout: col = lane&15, row = (lane>>4)*4 + reg
    int rowb = bm + (lane >> 4) * 4;
    int colb = w * 64 + (lane & 15);
#pragma unroll
    for (int mt = 0; mt < 4; ++mt) {
#pragma unroll
        for (int r = 0; r < 4; ++r) {
            int rr = rowb + mt * 16 + r;
            if (rr < M) {
#pragma unroll
                for (int g = 0; g < 4; ++g) {
                    int col = colb + g * 16;
                    float v = acc[mt][g][r];
                    if (bias4) {
                        v = 0.25f * (v + bias4[col] + bias4[col + 256] +
                                     bias4[col + 512] + bias4[col + 768]);
                    }
                    C[(size_t)rr * 256 + col] = v;
                }
            }
        }
    }

    // fused elr: el[rr,w] = sum_f z[rr, w*64+f]*alv[w*64+f] (f = (lane&15)+g*16)
    if (alv) {
        float alr[4], arr_[4];
#pragma unroll
        for (int g = 0; g < 4; ++g) {
            int f = w * 64 + (lane & 15) + g * 16;
            alr[g] = alv[f];
            arr_[g] = arv[f];
        }
#pragma unroll
        for (int mt = 0; mt < 4; ++mt) {
#pragma unroll
            for (int r = 0; r < 4; ++r) {
                float se = acc[mt][0][r] * alr[0] + acc[mt][1][r] * alr[1] +
                           acc[mt][2][r] * alr[2] + acc[mt][3][r] * alr[3];
                float sr = acc[mt][0][r] * arr_[0] + acc[mt][1][r] * arr_[1] +
                           acc[mt][2][r] * arr_[2] + acc[mt][3][r] * arr_[3];
                se += __shfl_xor(se, 1); se += __shfl_xor(se, 2);
                se += __shfl_xor(se, 4); se += __shfl_xor(se, 8);
                sr += __shfl_xor(sr, 1); sr += __shfl_xor(sr, 2);
                sr += __shfl_xor(sr, 4); sr += __shfl_xor(sr, 8);
                int rr = rowb + mt * 16 + r;
                if ((lane & 15) == 0 && rr < M) {
                    elo[rr * 4 + w] = se;
                    ero[rr * 4 + w] = sr;
                }
            }
        }
    }
}

// ---------------- attention score parts (layer 2) ----------------

// val[h*256+k] = sum_j W2[k,h*256+j]*al2[h,j] ; var likewise with ar2
__global__ __launch_bounds__(256) void proj_av_kernel(const float* __restrict__ W2,
                                                      const float* __restrict__ al2,
                                                      const float* __restrict__ ar2,
                                                      float* __restrict__ val,
                                                      float* __restrict__ var_) {
    int gid = blockIdx.x * 256 + threadIdx.x;
    int w = gid >> 6;
    int lane = threadIdx.x & 63;
    if (w >= 1024) return;
    int h = w >> 8, k = w & 255;
    const float* wrow = W2 + (size_t)k * 1024 + h * 256;
    const float* ap = al2 + h * 256;
    const float* rp = ar2 + h * 256;
    float sv = 0.f, sr = 0.f;
    for (int j = lane; j < 256; j += 64) {
        float x = wrow[j];
        sv += x * ap[j];
        sr += x * rp[j];
    }
#pragma unroll
    for (int off = 32; off > 0; off >>= 1) {
        sv += __shfl_down(sv, off);
        sr += __shfl_down(sr, off);
    }
    if (lane == 0) { val[w] = sv; var_[w] = sr; }
}

// el[n,h] = h1[n,:]·val[h,:], er likewise
__global__ __launch_bounds__(256) void elr2_kernel(const float* __restrict__ h1,
                                                   const float* __restrict__ val,
                                                   const float* __restrict__ var_,
                                                   float* __restrict__ el,
                                                   float* __restrict__ er) {
    int gid = blockIdx.x * 256 + threadIdx.x;
    int w = gid >> 6;
    int lane = threadIdx.x & 63;
    if (w >= NN * 4) return;
    int n = w >> 2, h = w & 3;
    const float* hr = h1 + (size_t)n * 256;
    const float* vp = val + h * 256;
    const float* rp = var_ + h * 256;
    float se = 0.f, sr = 0.f;
    for (int k = lane; k < 256; k += 64) {
        float x = hr[k];
        se += x * vp[k];
        sr += x * rp[k];
    }
#pragma unroll
    for (int off = 32; off > 0; off >>= 1) {
        se += __shfl_down(se, off);
        sr += __shfl_down(sr, off);
    }
    if (lane == 0) { el[w] = se; er[w] = sr; }
}

// ---------------- aggregation (byte-exact R0 bodies — do not touch) ----------------

// layer 0: elu epilogue, writes bf16 hi/lo row-major (consumed only by L1 GEMM)

__global__ __launch_bounds__(256) void agg_bf_kernel(const float* __restrict__ z,
                                                     const float* __restrict__ el,
                                                     const float* __restrict__ er,
                                                     const int* __restrict__ offs,
                                                     const int* __restrict__ psrc,
                                                     const float* __restrict__ bias,
                                                     short* __restrict__ ohi,
                                                     short* __restrict__ olo) {
    int n = blockIdx.x;
    int t = threadIdx.x;
    int h = t >> 6;
    __shared__ float p_lds[64][4];
    __shared__ int src_lds[64];
    __shared__ float den_lds[4];
    if (t < 4) den_lds[t] = 0.f;
    int beg = offs[n], end = offs[n + 1];
    float acc = 0.f;
    int e_local = t >> 2, hh = t & 3;
    float er_n = er[n * 4 + hh];
    for (int base = beg; base < end; base += 64) {
        int cnt = min(64, end - base);
        __syncthreads();
        if (e_local < cnt) {
            int s = psrc[base + e_local];
            if (hh == 0) src_lds[e_local] = s;
            float sc = el[s * 4 + hh] + er_n;
            sc = (sc > 0.f) ? sc : 0.2f * sc;
            float p = __expf(sc);
            p_lds[e_local][hh] = p;
            atomicAdd(&den_lds[hh], p);
        }
        __syncthreads();
        for (int e = 0; e < cnt; ++e) {
            acc += p_lds[e][h] * z[(size_t)src_lds[e] * 256 + t];
        }
    }
    __syncthreads();
    float o = acc / fmaxf(den_lds[h], 1e-9f) + bias[t];
    o = (o > 0.f) ? o : (__expf(o) - 1.f);
    short hv, lv;
    split1(o, hv, lv);
    ohi[(size_t)n * 256 + t] = hv;
    olo[(size_t)n * 256 + t] = lv;
}

// layer 1: elu epilogue, fp32 out (consumed by elr2 + aggH gathers)

__global__ __launch_bounds__(256) void agg_kernel(const float* __restrict__ z,
                                                  const float* __restrict__ el,
                                                  const float* __restrict__ er,
                                                  const int* __restrict__ offs,
                                                  const int* __restrict__ psrc,
                                                  const float* __restrict__ bias,
                                                  float* __restrict__ out) {
    int n = blockIdx.x;
    int t = threadIdx.x;
    int h = t >> 6;
    __shared__ float p_lds[64][4];
    __shared__ int src_lds[64];
    __shared__ float den_lds[4];
    if (t < 4) den_lds[t] = 0.f;
    int beg = offs[n], end = offs[n + 1];
    float acc = 0.f;
    int e_local = t >> 2, hh = t & 3;
    float er_n = er[n * 4 + hh];
    for (int base = beg; base < end; base += 64) {
        int cnt = min(64, end - base);
        __syncthreads();
        if (e_local < cnt) {
            int s = psrc[base + e_local];
            if (hh == 0) src_lds[e_local] = s;
            float sc = el[s * 4 + hh] + er_n;
            sc = (sc > 0.f) ? sc : 0.2f * sc;
            float p = __expf(sc);
            p_lds[e_local][hh] = p;
            atomicAdd(&den_lds[hh], p);
        }
        __syncthreads();
        for (int e = 0; e < cnt; ++e) {
            acc += p_lds[e][h] * z[(size_t)src_lds[e] * 256 + t];
        }
    }
    __syncthreads();
    float o = acc / fmaxf(den_lds[h], 1e-9f) + bias[t];
    out[(size_t)n * 256 + t] = (o > 0.f) ? o : (__expf(o) - 1.f);
}

// layer-2 aggregation of h1 -> bf16 hi/lo row-major [N,1024] (consumed only by fin GEMM)

__global__ __launch_bounds__(256) void aggH_bf_kernel(const float* __restrict__ h1,
                                                      const float* __restrict__ el,
                                                      const float* __restrict__ er,
                                                      const int* __restrict__ offs,
                                                      const int* __restrict__ psrc,
                                                      short* __restrict__ ohi,
                                                      short* __restrict__ olo) {
    int n = blockIdx.x, t = threadIdx.x;
    __shared__ float p_lds[64][4];
    __shared__ int src_lds[64];
    __shared__ float den_lds[4];
    if (t < 4) den_lds[t] = 0.f;
    int beg = offs[n], end = offs[n + 1];
    float a0 = 0.f, a1 = 0.f, a2 = 0.f, a3 = 0.f;
    int e_local = t >> 2, hh = t & 3;
    float er_n = er[n * 4 + hh];
    for (int base = beg; base < end; base += 64) {
        int cnt = min(64, end - base);
        __syncthreads();
        if (e_local < cnt) {
            int s = psrc[base + e_local];
            if (hh == 0) src_lds[e_local] = s;
            float sc = el[s * 4 + hh] + er_n;
            sc = (sc > 0.f) ? sc : 0.2f * sc;
            float p = __expf(sc);
            p_lds[e_local][hh] = p;
            atomicAdd(&den_lds[hh], p);
        }
        __syncthreads();
        for (int e = 0; e < cnt; ++e) {
            float v = h1[(size_t)src_lds[e] * 256 + t];
            a0 += p_lds[e][0] * v;
            a1 += p_lds[e][1] * v;
            a2 += p_lds[e][2] * v;
            a3 += p_lds[e][3] * v;
        }
    }
    __syncthreads();
    float vals[4];
    vals[0] = a0 / fmaxf(den_lds[0], 1e-9f);
    vals[1] = a1 / fmaxf(den_lds[1], 1e-9f);
    vals[2] = a2 / fmaxf(den_lds[2], 1e-9f);
    vals[3] = a3 / fmaxf(den_lds[3], 1e-9f);
    size_t base_o = (size_t)n * 1024 + t;
#pragma unroll
    for (int h = 0; h < 4; ++h) {
        short hv, lv;
        split1(vals[h], hv, lv);
        ohi[base_o + h * 256] = hv;
        olo[base_o + h * 256] = lv;
    }
}

// ---------------- launch ----------------

extern "C" void kernel_launch(void* const* d_in, const int* in_sizes, int n_in,
                              void* d_out, int out_size, void* d_ws, size_t ws_size,
                              hipStream_t stream) {
    const float* feat = (const float*)d_in[0];
    const float* W0 = (const float*)d_in[1];
    const float* al0 = (const float*)d_in[2];
    const float* ar0 = (const float*)d_in[3];
    const float* b0 = (const float*)d_in[4];
    const float* W1 = (const float*)d_in[5];
    const float* al1 = (const float*)d_in[6];
    const float* ar1 = (const float*)d_in[7];
    const float* b1 = (const float*)d_in[8];
    const float* W2 = (const float*)d_in[9];
    const float* al2 = (const float*)d_in[10];
    const float* ar2 = (const float*)d_in[11];
    const float* b2 = (const float*)d_in[12];
    const int* src = (const int*)d_in[13];
    const int* dst = (const int*)d_in[14];
    float* out = (float*)d_out;

    // ---- workspace layout (~262.5 MB), time-multiplexed big slots ----
    float* slotA = (float*)d_ws;
    float* z = slotA;                                     // [N,256] fp32
    short* feathi = (short*)(slotA + (size_t)NN * 256);   // 50000*128 shorts
    short* featlo = feathi + (size_t)NN * 128;
    short* Ahi = (short*)slotA;                           // [N,1024] shorts (layer 2)
    short* Alo = Ahi + (size_t)NN * 1024;
    float* slotB = slotA + (size_t)NN * 1024;
    short* h0hi = (short*)slotB;                          // 50000*256 shorts
    short* h0lo = h0hi + (size_t)NN * 256;
    float* h1 = slotB;                                    // [N,256] fp32 (layer 2)
    float* el = slotB + (size_t)NN * 256;                 // 200000
    float* er = el + (size_t)NN * NH_HEADS;               // 200000
    int* deg = (int*)(er + (size_t)NN * NH_HEADS);        // 50000
    int* offs = deg + NN;                                 // 50001 (+1 pad)
    int* cursor = offs + NN + 2;                          // 50000
    int* bsums = cursor + NN;                             // 256
    int* boffs = bsums + 256;                             // 256
    int* psrc = boffs + 256;                              // 800000 (+2 pad)
    short* Bh = (short*)(psrc + NE + 2);                  // 262144 shorts
    short* Bl = Bh + 262144;                              // 262144 shorts
    float* val = (float*)(Bl + 262144);                   // 1024
    float* var_ = val + 1024;                             // 1024

    // ---- CSR build (by dst) ----
    hipMemsetAsync(deg, 0, NN * sizeof(int), stream);
    hist_kernel<<<(NE + 255) / 256, 256, 0, stream>>>(dst, deg, NE);
    int nb = (NN + 255) / 256;
    scan_block_kernel<<<nb, 256, 0, stream>>>(deg, offs, bsums, NN);
    scan_sums_kernel<<<1, 256, 0, stream>>>(bsums, boffs, nb);
    add_offs_kernel<<<nb, 256, 0, stream>>>(offs, boffs, cursor, NN, NE);
    scatter_kernel<<<(NE + 255) / 256, 256, 0, stream>>>(src, dst, cursor, psrc, NE);

    int mb64 = (NN + 63) / 64; // 782

    // ---- layer 0: 128 -> 4x64, elu (elr fused into GEMM epilogue) ----
    splitA_rm<<<(NN * 128 / 8 + 255) / 256, 256, 0, stream>>>(feat, feathi, featlo, NN * 128 / 8);
    splitB_kernel<<<(4096 + 255) / 256, 256, 0, stream>>>(W0, Bh, Bl, 128, 256);
    gemm_n256l<<<mb64, 256, 0, stream>>>(feathi, featlo, Bh, Bl, nullptr, z,
                                         al0, ar0, el, er, NN, 128);
    agg_bf_kernel<<<NN, 256, 0, stream>>>(z, el, er, offs, psrc, b0, h0hi, h0lo);

    // ---- layer 1: 256 -> 4x64, elu (elr fused into GEMM epilogue) ----
    splitB_kernel<<<(8192 + 255) / 256, 256, 0, stream>>>(W1, Bh, Bl, 256, 256);
    gemm_n256l<<<mb64, 256, 0, stream>>>(h0hi, h0lo, Bh, Bl, nullptr, z,
                                         al1, ar1, el, er, NN, 256);
    agg_kernel<<<NN, 256, 0, stream>>>(z, el, er, offs, psrc, b1, h1);

    // ---- layer 2 (restructured): score from aggregated h1, then project ----
    proj_av_kernel<<<256, 256, 0, stream>>>(W2, al2, ar2, val, var_);
    elr2_kernel<<<NN, 256, 0, stream>>>(h1, val, var_, el, er);
    aggH_bf_kernel<<<NN, 256, 0, stream>>>(h1, el, er, offs, psrc, Ahi, Alo);
    splitB2_kernel<<<(32768 + 255) / 256, 256, 0, stream>>>(W2, Bh, Bl);
    gemm_n256l<<<mb64, 256, 0, stream>>>(Ahi, Alo, Bh, Bl, b2, out,
                                         nullptr, nullptr, nullptr, nullptr, NN, 1024);
}

// Round 10
// 765.225 us; speedup vs baseline: 1.0991x; 1.0824x over previous
//
#include <hip/hip_runtime.h>
#include <hip/hip_bf16.h>

// GAT: 3 layers. N=50000 nodes, E=800000 edges, H=4 heads.
// R7: GEMM = m97-style 2-barrier K-loop, bf16 hi/lo split A/B.
// R13: elr fused into GEMM epilogue (worth ~27us).
// R16: elr2 UNfused (fused epilogue cost ~50us in agg_kernel); R0 gather
// bodies restored. 828.3us. Aggregations at the 4.3TB/s L3->L2 path
// ceiling; FETCH = 8 XCD x array size (z/h1 L3-resident, duplicated into
// every XCD L2) -> bytes/element is the only remaining lever.
// R17: fp16 gather arrays. z and h1 are consumed ONLY by gathers (el/er
// come from fp32 acc in the GEMM epilogue, pre-quantization). Storing
// them fp16 halves gather fetch (205MB/kernel) + h1 write. GEMM A/B
// stay bf16 hi/lo; logits stay fp32. Est. absmax 4.9e-4 -> ~6-9e-4.

#define NN 50000
#define NE 800000
#define NH_HEADS 4

typedef __attribute__((ext_vector_type(8))) short short8;
typedef __attribute__((ext_vector_type(4))) float floatx4;

__device__ inline float bf2f(short s) {
    union { unsigned u; float f; } v; v.u = ((unsigned)(unsigned short)s) << 16;
    return v.f;
}
__device__ inline short f2bf_rne(float x) {
    union { float f; unsigned u; } v; v.f = x;
    unsigned r = v.u + 0x7fff + ((v.u >> 16) & 1);
    return (short)(r >> 16);
}
// truncation hi/lo split: hi = trunc16(x), lo = trunc16(x - hi)
__device__ inline void split1(float x, short& h, short& l) {
    union { float f; unsigned u; } v; v.f = x;
    h = (short)(v.u >> 16);
    union { float f; unsigned u; } rv; rv.f = v.f - bf2f(h);
    l = (short)(rv.u >> 16);
}

// async 16B/lane global->LDS; lds base must be wave-uniform (dest = base + lane*16)
__device__ inline void load_lds16(const short* g, short* l) {
    __builtin_amdgcn_global_load_lds(
        (const __attribute__((address_space(1))) void*)g,
        (__attribute__((address_space(3))) void*)l, 16, 0, 0);
}

// ---------------- CSR build ----------------

__global__ void hist_kernel(const int* __restrict__ dst, int* __restrict__ deg, int E) {
    int e = blockIdx.x * 256 + threadIdx.x;
    if (e < E) atomicAdd(&deg[dst[e]], 1);
}

__global__ void scan_block_kernel(const int* __restrict__ deg, int* __restrict__ offs,
                                  int* __restrict__ bsums, int n) {
    __shared__ int s[256];
    int tid = threadIdx.x;
    int i = blockIdx.x * 256 + tid;
    int v = (i < n) ? deg[i] : 0;
    s[tid] = v;
    __syncthreads();
    for (int off = 1; off < 256; off <<= 1) {
        int x = (tid >= off) ? s[tid - off] : 0;
        __syncthreads();
        s[tid] += x;
        __syncthreads();
    }
    if (i < n) offs[i] = s[tid] - v;
    if (tid == 255) bsums[blockIdx.x] = s[255];
}

__global__ void scan_sums_kernel(const int* __restrict__ bsums, int* __restrict__ boffs, int nb) {
    __shared__ int s[256];
    int tid = threadIdx.x;
    int v = (tid < nb) ? bsums[tid] : 0;
    s[tid] = v;
    __syncthreads();
    for (int off = 1; off < 256; off <<= 1) {
        int x = (tid >= off) ? s[tid - off] : 0;
        __syncthreads();
        s[tid] += x;
        __syncthreads();
    }
    boffs[tid] = s[tid] - v;
}

__global__ void add_offs_kernel(int* __restrict__ offs, const int* __restrict__ boffs,
                                int* __restrict__ cursor, int n, int total) {
    int i = blockIdx.x * 256 + threadIdx.x;
    if (i < n) {
        int o = offs[i] + boffs[blockIdx.x];
        offs[i] = o;
        cursor[i] = o;
    }
    if (i == 0) offs[n] = total;
}

__global__ void scatter_kernel(const int* __restrict__ src, const int* __restrict__ dst,
                               int* __restrict__ cursor, int* __restrict__ psrc, int E) {
    int e = blockIdx.x * 256 + threadIdx.x;
    if (e < E) {
        int p = atomicAdd(&cursor[dst[e]], 1);
        psrc[p] = src[e];
    }
}

// ---------------- A (row-major fp32) -> row-major bf16 hi/lo ----------------

__global__ __launch_bounds__(256) void splitA_rm(const float* __restrict__ A,
                                                 short* __restrict__ hi,
                                                 short* __restrict__ lo,
                                                 int total8) {
    int tid = blockIdx.x * 256 + threadIdx.x;
    if (tid >= total8) return;
    const float* p = A + (size_t)tid * 8;
    float4 x0 = ((const float4*)p)[0];
    float4 x1 = ((const float4*)p)[1];
    float xs[8] = {x0.x, x0.y, x0.z, x0.w, x1.x, x1.y, x1.z, x1.w};
    short8 hv, lv;
#pragma unroll
    for (int j = 0; j < 8; ++j) { short h, l; split1(xs[j], h, l); hv[j] = h; lv[j] = l; }
    ((short8*)hi)[tid] = hv;
    ((short8*)lo)[tid] = lv;
}

// ---------------- B -> bf16 hi/lo in MFMA B-fragment order ----------------
// offset (short8) = (c*(N/16)+g)*64 + lane ; lane=(n&15)+16*((k&31)>>3), j=k&7

__global__ __launch_bounds__(256) void splitB_kernel(const float* __restrict__ B,
                                                     short* __restrict__ hi,
                                                     short* __restrict__ lo,
                                                     int K, int N) {
    int tid = blockIdx.x * 256 + threadIdx.x;
    int NG = N >> 4;
    int total = (K >> 5) * NG * 64;
    if (tid >= total) return;
    int lane = tid & 63;
    int rc = tid >> 6;
    int g = rc % NG, c = rc / NG;
    int n = g * 16 + (lane & 15);
    int k = c * 32 + (lane >> 4) * 8;
    short8 hv, lv;
#pragma unroll
    for (int j = 0; j < 8; ++j) {
        float x = B[(size_t)(k + j) * N + n];
        short h = f2bf_rne(x);
        hv[j] = h;
        lv[j] = f2bf_rne(x - bf2f(h));
    }
    ((short8*)hi)[tid] = hv;
    ((short8*)lo)[tid] = lv;
}

// permuted-W2: Bp[h*256+k, c] = W2[k, h*256+c]; K=1024, N=256
__global__ __launch_bounds__(256) void splitB2_kernel(const float* __restrict__ W2,
                                                      short* __restrict__ hi,
                                                      short* __restrict__ lo) {
    int tid = blockIdx.x * 256 + threadIdx.x;
    const int NG = 16;
    int total = (1024 >> 5) * NG * 64;   // 32768
    if (tid >= total) return;
    int lane = tid & 63;
    int rc = tid >> 6;
    int g = rc % NG, c = rc / NG;
    int n = g * 16 + (lane & 15);
    int kk = c * 32 + (lane >> 4) * 8;
    short8 hv, lv;
#pragma unroll
    for (int j = 0; j < 8; ++j) {
        int kg = kk + j;
        int h = kg >> 8, k = kg & 255;
        float x = W2[(size_t)k * 1024 + h * 256 + n];
        short hb = f2bf_rne(x);
        hv[j] = hb;
        lv[j] = f2bf_rne(x - bf2f(hb));
    }
    ((short8*)hi)[tid] = hv;
    ((short8*)lo)[tid] = lv;
}

// ---------------- MFMA GEMM, N=256, A via async LDS staging ----------------
// block: 64 rows x 256 cols; wave w owns rows [bm,bm+64) x cols [w*64,(w+1)*64).
// C-write: fp32 (C) or fp16 (Cf) — exactly one non-null.
// Optional fused elr epilogue (alv!=null): wave w = head w computes
// el[n,w] = z[n, w*64..w*64+64) . alv[w], er likewise, from fp32 acc
// (pre-quantization), via 4 FMA + 4-step shfl_xor reduce.

__device__ inline floatx4 mfma16(short8 a, short8 b, floatx4 c) {
    return __builtin_amdgcn_mfma_f32_16x16x32_bf16(a, b, c, 0, 0, 0);
}

__global__ __launch_bounds__(256) void gemm_n256l(const short* __restrict__ Ahi,
                                                  const short* __restrict__ Alo,
                                                  const short* __restrict__ Bh,
                                                  const short* __restrict__ Bl,
                                                  const float* __restrict__ bias4,
                                                  float* __restrict__ C,
                                                  _Float16* __restrict__ Cf,
                                                  const float* __restrict__ alv,
                                                  const float* __restrict__ arv,
                                                  float* __restrict__ elo,
                                                  float* __restrict__ ero,
                                                  int M, int K) {
    int KC = K >> 5;
    __shared__ short AhL[2048];   // 4 m-tiles x 64 lanes x 8 shorts = 4 KB
    __shared__ short AlL[2048];
    int t = threadIdx.x;
    int lane = t & 63;
    int w = t >> 6;
    int bm = blockIdx.x * 64;
    int g0 = w * 4;
    const short8* pBh = (const short8*)Bh;
    const short8* pBl = (const short8*)Bl;

    floatx4 acc[4][4] = {};

    // staging source for this lane (m-tile w)
    int row = bm + (w << 4) + (lane & 15);
    if (row >= M) row = M - 1;                    // clamp: junk rows never stored
    const short* gh = Ahi + (size_t)row * K + ((lane >> 4) << 3);
    const short* gl = Alo + (size_t)row * K + ((lane >> 4) << 3);
    short* lh = AhL + w * 512;                    // wave-uniform LDS base
    short* ll = AlL + w * 512;

    for (int c = 0; c < KC; ++c) {
        load_lds16(gh + (size_t)c * 32, lh);
        load_lds16(gl + (size_t)c * 32, ll);
        short8 bh[4], bl[4];
#pragma unroll
        for (int g = 0; g < 4; ++g) {
            bh[g] = pBh[((size_t)c * (256 / 16) + g0 + g) * 64 + lane];
            bl[g] = pBl[((size_t)c * (256 / 16) + g0 + g) * 64 + lane];
        }
        __syncthreads();   // drains vmcnt: LDS staged, B regs ready
#pragma unroll
        for (int mt = 0; mt < 4; ++mt) {
            short8 ah = *(const short8*)(AhL + mt * 512 + lane * 8);
            short8 al = *(const short8*)(AlL + mt * 512 + lane * 8);
#pragma unroll
            for (int g = 0; g < 4; ++g) {
                acc[mt][g] = mfma16(ah, bh[g], acc[mt][g]);
                acc[mt][g] = mfma16(al, bh[g], acc[mt][g]);
                acc[mt][g] = mfma16(ah, bl[g], acc[mt][g]);
            }
        }
        __syncthreads();   // all LDS reads done before next overwrite
    }

    // C/D layout: col = lane&15, row = (lane>>4)*4 + reg
    int rowb = bm + (lane >> 4) * 4;
    int colb = w * 64 + (lane & 15);
#pragma unroll
    for (int mt = 0; mt < 4; ++mt) {
#pragma unroll
        for (int r = 0; r < 4; ++r) {
            int rr = rowb + mt * 16 + r;
            if (rr < M) {
#pragma unroll
                for (int g = 0; g < 4; ++g) {
                    int col = colb + g * 16;
                    float v = acc[mt][g][r];
                    if (bias4) {
                        v = 0.25f * (v + bias4[col] + bias4[col + 256] +
                                     bias4[col + 512] + bias4[col + 768]);
                    }
                    if (Cf) Cf[(size_t)rr * 256 + col] = (_Float16)v;
                    else    C[(size_t)rr * 256 + col] = v;
                }
            }
        }
    }

    // fused elr: el[rr,w] = sum_f z[rr, w*64+f]*alv[w*64+f] (f = (lane&15)+g*16)
    if (alv) {
        float alr[4], arr_[4];
#pragma unroll
        for (int g = 0; g < 4; ++g) {
            int f = w * 64 + (lane & 15) + g * 16;
            alr[g] = alv[f];
            arr_[g] = arv[f];
        }
#pragma unroll
        for (int mt = 0; mt < 4; ++mt) {
#pragma unroll
            for (int r = 0; r < 4; ++r) {
                float se = acc[mt][0][r] * alr[0] + acc[mt][1][r] * alr[1] +
                           acc[mt][2][r] * alr[2] + acc[mt][3][r] * alr[3];
                float sr = acc[mt][0][r] * arr_[0] + acc[mt][1][r] * arr_[1] +
                           acc[mt][2][r] * arr_[2] + acc[mt][3][r] * arr_[3];
                se += __shfl_xor(se, 1); se += __shfl_xor(se, 2);
                se += __shfl_xor(se, 4); se += __shfl_xor(se, 8);
                sr += __shfl_xor(sr, 1); sr += __shfl_xor(sr, 2);
                sr += __shfl_xor(sr, 4); sr += __shfl_xor(sr, 8);
                int rr = rowb + mt * 16 + r;
                if ((lane & 15) == 0 && rr < M) {
                    elo[rr * 4 + w] = se;
                    ero[rr * 4 + w] = sr;
                }
            }
        }
    }
}

// ---------------- attention score parts (layer 2) ----------------

// val[h*256+k] = sum_j W2[k,h*256+j]*al2[h,j] ; var likewise with ar2
__global__ __launch_bounds__(256) void proj_av_kernel(const float* __restrict__ W2,
                                                      const float* __restrict__ al2,
                                                      const float* __restrict__ ar2,
                                                      float* __restrict__ val,
                                                      float* __restrict__ var_) {
    int gid = blockIdx.x * 256 + threadIdx.x;
    int w = gid >> 6;
    int lane = threadIdx.x & 63;
    if (w >= 1024) return;
    int h = w >> 8, k = w & 255;
    const float* wrow = W2 + (size_t)k * 1024 + h * 256;
    const float* ap = al2 + h * 256;
    const float* rp = ar2 + h * 256;
    float sv = 0.f, sr = 0.f;
    for (int j = lane; j < 256; j += 64) {
        float x = wrow[j];
        sv += x * ap[j];
        sr += x * rp[j];
    }
#pragma unroll
    for (int off = 32; off > 0; off >>= 1) {
        sv += __shfl_down(sv, off);
        sr += __shfl_down(sr, off);
    }
    if (lane == 0) { val[w] = sv; var_[w] = sr; }
}

// el[n,h] = h1[n,:]·val[h,:], er likewise (h1 fp16)
__global__ __launch_bounds__(256) void elr2_kernel(const _Float16* __restrict__ h1,
                                                   const float* __restrict__ val,
                                                   const float* __restrict__ var_,
                                                   float* __restrict__ el,
                                                   float* __restrict__ er) {
    int gid = blockIdx.x * 256 + threadIdx.x;
    int w = gid >> 6;
    int lane = threadIdx.x & 63;
    if (w >= NN * 4) return;
    int n = w >> 2, h = w & 3;
    const _Float16* hr = h1 + (size_t)n * 256;
    const float* vp = val + h * 256;
    const float* rp = var_ + h * 256;
    float se = 0.f, sr = 0.f;
    for (int k = lane; k < 256; k += 64) {
        float x = (float)hr[k];
        se += x * vp[k];
        sr += x * rp[k];
    }
#pragma unroll
    for (int off = 32; off > 0; off >>= 1) {
        se += __shfl_down(se, off);
        sr += __shfl_down(sr, off);
    }
    if (lane == 0) { el[w] = se; er[w] = sr; }
}

// ---------------- aggregation (R0 loop bodies; fp16 gather arrays) ----------------

// layer 0: elu epilogue, writes bf16 hi/lo row-major (consumed only by L1 GEMM)

__global__ __launch_bounds__(256) void agg_bf_kernel(const _Float16* __restrict__ z,
                                                     const float* __restrict__ el,
                                                     const float* __restrict__ er,
                                                     const int* __restrict__ offs,
                                                     const int* __restrict__ psrc,
                                                     const float* __restrict__ bias,
                                                     short* __restrict__ ohi,
                                                     short* __restrict__ olo) {
    int n = blockIdx.x;
    int t = threadIdx.x;
    int h = t >> 6;
    __shared__ float p_lds[64][4];
    __shared__ int src_lds[64];
    __shared__ float den_lds[4];
    if (t < 4) den_lds[t] = 0.f;
    int beg = offs[n], end = offs[n + 1];
    float acc = 0.f;
    int e_local = t >> 2, hh = t & 3;
    float er_n = er[n * 4 + hh];
    for (int base = beg; base < end; base += 64) {
        int cnt = min(64, end - base);
        __syncthreads();
        if (e_local < cnt) {
            int s = psrc[base + e_local];
            if (hh == 0) src_lds[e_local] = s;
            float sc = el[s * 4 + hh] + er_n;
            sc = (sc > 0.f) ? sc : 0.2f * sc;
            float p = __expf(sc);
            p_lds[e_local][hh] = p;
            atomicAdd(&den_lds[hh], p);
        }
        __syncthreads();
        for (int e = 0; e < cnt; ++e) {
            acc += p_lds[e][h] * (float)z[(size_t)src_lds[e] * 256 + t];
        }
    }
    __syncthreads();
    float o = acc / fmaxf(den_lds[h], 1e-9f) + bias[t];
    o = (o > 0.f) ? o : (__expf(o) - 1.f);
    short hv, lv;
    split1(o, hv, lv);
    ohi[(size_t)n * 256 + t] = hv;
    olo[(size_t)n * 256 + t] = lv;
}

// layer 1: elu epilogue, fp16 out (consumed by elr2 + aggH gathers)

__global__ __launch_bounds__(256) void agg_kernel(const _Float16* __restrict__ z,
                                                  const float* __restrict__ el,
                                                  const float* __restrict__ er,
                                                  const int* __restrict__ offs,
                                                  const int* __restrict__ psrc,
                                                  const float* __restrict__ bias,
                                                  _Float16* __restrict__ out) {
    int n = blockIdx.x;
    int t = threadIdx.x;
    int h = t >> 6;
    __shared__ float p_lds[64][4];
    __shared__ int src_lds[64];
    __shared__ float den_lds[4];
    if (t < 4) den_lds[t] = 0.f;
    int beg = offs[n], end = offs[n + 1];
    float acc = 0.f;
    int e_local = t >> 2, hh = t & 3;
    float er_n = er[n * 4 + hh];
    for (int base = beg; base < end; base += 64) {
        int cnt = min(64, end - base);
        __syncthreads();
        if (e_local < cnt) {
            int s = psrc[base + e_local];
            if (hh == 0) src_lds[e_local] = s;
            float sc = el[s * 4 + hh] + er_n;
            sc = (sc > 0.f) ? sc : 0.2f * sc;
            float p = __expf(sc);
            p_lds[e_local][hh] = p;
            atomicAdd(&den_lds[hh], p);
        }
        __syncthreads();
        for (int e = 0; e < cnt; ++e) {
            acc += p_lds[e][h] * (float)z[(size_t)src_lds[e] * 256 + t];
        }
    }
    __syncthreads();
    float o = acc / fmaxf(den_lds[h], 1e-9f) + bias[t];
    o = (o > 0.f) ? o : (__expf(o) - 1.f);
    out[(size_t)n * 256 + t] = (_Float16)o;
}

// layer-2 aggregation of h1 (fp16) -> bf16 hi/lo [N,1024] (consumed by fin GEMM)

__global__ __launch_bounds__(256) void aggH_bf_kernel(const _Float16* __restrict__ h1,
                                                      const float* __restrict__ el,
                                                      const float* __restrict__ er,
                                                      const int* __restrict__ offs,
                                                      const int* __restrict__ psrc,
                                                      short* __restrict__ ohi,
                                                      short* __restrict__ olo) {
    int n = blockIdx.x, t = threadIdx.x;
    __shared__ float p_lds[64][4];
    __shared__ int src_lds[64];
    __shared__ float den_lds[4];
    if (t < 4) den_lds[t] = 0.f;
    int beg = offs[n], end = offs[n + 1];
    float a0 = 0.f, a1 = 0.f, a2 = 0.f, a3 = 0.f;
    int e_local = t >> 2, hh = t & 3;
    float er_n = er[n * 4 + hh];
    for (int base = beg; base < end; base += 64) {
        int cnt = min(64, end - base);
        __syncthreads();
        if (e_local < cnt) {
            int s = psrc[base + e_local];
            if (hh == 0) src_lds[e_local] = s;
            float sc = el[s * 4 + hh] + er_n;
            sc = (sc > 0.f) ? sc : 0.2f * sc;
            float p = __expf(sc);
            p_lds[e_local][hh] = p;
            atomicAdd(&den_lds[hh], p);
        }
        __syncthreads();
        for (int e = 0; e < cnt; ++e) {
            float v = (float)h1[(size_t)src_lds[e] * 256 + t];
            a0 += p_lds[e][0] * v;
            a1 += p_lds[e][1] * v;
            a2 += p_lds[e][2] * v;
            a3 += p_lds[e][3] * v;
        }
    }
    __syncthreads();
    float vals[4];
    vals[0] = a0 / fmaxf(den_lds[0], 1e-9f);
    vals[1] = a1 / fmaxf(den_lds[1], 1e-9f);
    vals[2] = a2 / fmaxf(den_lds[2], 1e-9f);
    vals[3] = a3 / fmaxf(den_lds[3], 1e-9f);
    size_t base_o = (size_t)n * 1024 + t;
#pragma unroll
    for (int h = 0; h < 4; ++h) {
        short hv, lv;
        split1(vals[h], hv, lv);
        ohi[base_o + h * 256] = hv;
        olo[base_o + h * 256] = lv;
    }
}

// ---------------- launch ----------------

extern "C" void kernel_launch(void* const* d_in, const int* in_sizes, int n_in,
                              void* d_out, int out_size, void* d_ws, size_t ws_size,
                              hipStream_t stream) {
    const float* feat = (const float*)d_in[0];
    const float* W0 = (const float*)d_in[1];
    const float* al0 = (const float*)d_in[2];
    const float* ar0 = (const float*)d_in[3];
    const float* b0 = (const float*)d_in[4];
    const float* W1 = (const float*)d_in[5];
    const float* al1 = (const float*)d_in[6];
    const float* ar1 = (const float*)d_in[7];
    const float* b1 = (const float*)d_in[8];
    const float* W2 = (const float*)d_in[9];
    const float* al2 = (const float*)d_in[10];
    const float* ar2 = (const float*)d_in[11];
    const float* b2 = (const float*)d_in[12];
    const int* src = (const int*)d_in[13];
    const int* dst = (const int*)d_in[14];
    float* out = (float*)d_out;

    // ---- workspace layout (~262.5 MB), time-multiplexed big slots ----
    float* slotA = (float*)d_ws;
    _Float16* zh = (_Float16*)slotA;                      // [N,256] fp16 (z slot)
    short* feathi = (short*)(slotA + (size_t)NN * 256);   // 50000*128 shorts
    short* featlo = feathi + (size_t)NN * 128;
    short* Ahi = (short*)slotA;                           // [N,1024] shorts (layer 2)
    short* Alo = Ahi + (size_t)NN * 1024;
    float* slotB = slotA + (size_t)NN * 1024;
    short* h0hi = (short*)slotB;                          // 50000*256 shorts
    short* h0lo = h0hi + (size_t)NN * 256;
    _Float16* h1h = (_Float16*)slotB;                     // [N,256] fp16 (layer 2)
    float* el = slotB + (size_t)NN * 256;                 // 200000
    float* er = el + (size_t)NN * NH_HEADS;               // 200000
    int* deg = (int*)(er + (size_t)NN * NH_HEADS);        // 50000
    int* offs = deg + NN;                                 // 50001 (+1 pad)
    int* cursor = offs + NN + 2;                          // 50000
    int* bsums = cursor + NN;                             // 256
    int* boffs = bsums + 256;                             // 256
    int* psrc = boffs + 256;                              // 800000 (+2 pad)
    short* Bh = (short*)(psrc + NE + 2);                  // 262144 shorts
    short* Bl = Bh + 262144;                              // 262144 shorts
    float* val = (float*)(Bl + 262144);                   // 1024
    float* var_ = val + 1024;                             // 1024

    // ---- CSR build (by dst) ----
    hipMemsetAsync(deg, 0, NN * sizeof(int), stream);
    hist_kernel<<<(NE + 255) / 256, 256, 0, stream>>>(dst, deg, NE);
    int nb = (NN + 255) / 256;
    scan_block_kernel<<<nb, 256, 0, stream>>>(deg, offs, bsums, NN);
    scan_sums_kernel<<<1, 256, 0, stream>>>(bsums, boffs, nb);
    add_offs_kernel<<<nb, 256, 0, stream>>>(offs, boffs, cursor, NN, NE);
    scatter_kernel<<<(NE + 255) / 256, 256, 0, stream>>>(src, dst, cursor, psrc, NE);

    int mb64 = (NN + 63) / 64; // 782

    // ---- layer 0: 128 -> 4x64, elu (elr fused into GEMM epilogue; z fp16) ----
    splitA_rm<<<(NN * 128 / 8 + 255) / 256, 256, 0, stream>>>(feat, feathi, featlo, NN * 128 / 8);
    splitB_kernel<<<(4096 + 255) / 256, 256, 0, stream>>>(W0, Bh, Bl, 128, 256);
    gemm_n256l<<<mb64, 256, 0, stream>>>(feathi, featlo, Bh, Bl, nullptr,
                                         nullptr, zh, al0, ar0, el, er, NN, 128);
    agg_bf_kernel<<<NN, 256, 0, stream>>>(zh, el, er, offs, psrc, b0, h0hi, h0lo);

    // ---- layer 1: 256 -> 4x64, elu (elr fused; z2 fp16; h1 fp16) ----
    splitB_kernel<<<(8192 + 255) / 256, 256, 0, stream>>>(W1, Bh, Bl, 256, 256);
    gemm_n256l<<<mb64, 256, 0, stream>>>(h0hi, h0lo, Bh, Bl, nullptr,
                                         nullptr, zh, al1, ar1, el, er, NN, 256);
    agg_kernel<<<NN, 256, 0, stream>>>(zh, el, er, offs, psrc, b1, h1h);

    // ---- layer 2 (restructured): score from aggregated h1, then project ----
    proj_av_kernel<<<256, 256, 0, stream>>>(W2, al2, ar2, val, var_);
    elr2_kernel<<<NN, 256, 0, stream>>>(h1h, val, var_, el, er);
    aggH_bf_kernel<<<NN, 256, 0, stream>>>(h1h, el, er, offs, psrc, Ahi, Alo);
    splitB2_kernel<<<(32768 + 255) / 256, 256, 0, stream>>>(W2, Bh, Bl);
    gemm_n256l<<<mb64, 256, 0, stream>>>(Ahi, Alo, Bh, Bl, b2,
                                         out, nullptr, nullptr, nullptr, nullptr, nullptr,
                                         NN, 1024);
}

// Round 12
// 735.759 us; speedup vs baseline: 1.1431x; 1.0400x over previous
//
#include <hip/hip_runtime.h>
#include <hip/hip_bf16.h>

// GAT: 3 layers. N=50000 nodes, E=800000 edges, H=4 heads.
// R13/R16: elr fused into GEMM epilogue; elr2 separate. R17: fp16 gather
// arrays (z,h1) -> 765.2us, absmax unchanged (error budget elsewhere).
// R18: f16-native GEMM path. h1/h0 are fp16 already -> use
// mfma_f32_16x16x32_f16 with A as a SINGLE f16 operand (exact) and the
// hi/lo split on B only (f16 pair, better than bf16 pair): 2 MFMAs per
// fragment instead of 3, half the A bytes/staging. Applied to L1 (h0
// stored single f16) and final K=1024 GEMM (aggH writes single f16
// [N,1024], 102MB not 205MB). L0 keeps bf16-pair A (feat is fp32).
// R19: resubmit of R18 (container infra failure, no counters returned).

#define NN 50000
#define NE 800000
#define NH_HEADS 4

typedef __attribute__((ext_vector_type(8))) short short8;
typedef __attribute__((ext_vector_type(8))) _Float16 half8;
typedef __attribute__((ext_vector_type(4))) float floatx4;

__device__ inline float bf2f(short s) {
    union { unsigned u; float f; } v; v.u = ((unsigned)(unsigned short)s) << 16;
    return v.f;
}
__device__ inline short f2bf_rne(float x) {
    union { float f; unsigned u; } v; v.f = x;
    unsigned r = v.u + 0x7fff + ((v.u >> 16) & 1);
    return (short)(r >> 16);
}
// truncation hi/lo split: hi = trunc16(x), lo = trunc16(x - hi)
__device__ inline void split1(float x, short& h, short& l) {
    union { float f; unsigned u; } v; v.f = x;
    h = (short)(v.u >> 16);
    union { float f; unsigned u; } rv; rv.f = v.f - bf2f(h);
    l = (short)(rv.u >> 16);
}

// async 16B/lane global->LDS; lds base must be wave-uniform (dest = base + lane*16)
__device__ inline void load_lds16(const void* g, void* l) {
    __builtin_amdgcn_global_load_lds(
        (const __attribute__((address_space(1))) void*)g,
        (__attribute__((address_space(3))) void*)l, 16, 0, 0);
}

// ---------------- CSR build ----------------

__global__ void hist_kernel(const int* __restrict__ dst, int* __restrict__ deg, int E) {
    int e = blockIdx.x * 256 + threadIdx.x;
    if (e < E) atomicAdd(&deg[dst[e]], 1);
}

__global__ void scan_block_kernel(const int* __restrict__ deg, int* __restrict__ offs,
                                  int* __restrict__ bsums, int n) {
    __shared__ int s[256];
    int tid = threadIdx.x;
    int i = blockIdx.x * 256 + tid;
    int v = (i < n) ? deg[i] : 0;
    s[tid] = v;
    __syncthreads();
    for (int off = 1; off < 256; off <<= 1) {
        int x = (tid >= off) ? s[tid - off] : 0;
        __syncthreads();
        s[tid] += x;
        __syncthreads();
    }
    if (i < n) offs[i] = s[tid] - v;
    if (tid == 255) bsums[blockIdx.x] = s[255];
}

__global__ void scan_sums_kernel(const int* __restrict__ bsums, int* __restrict__ boffs, int nb) {
    __shared__ int s[256];
    int tid = threadIdx.x;
    int v = (tid < nb) ? bsums[tid] : 0;
    s[tid] = v;
    __syncthreads();
    for (int off = 1; off < 256; off <<= 1) {
        int x = (tid >= off) ? s[tid - off] : 0;
        __syncthreads();
        s[tid] += x;
        __syncthreads();
    }
    boffs[tid] = s[tid] - v;
}

__global__ void add_offs_kernel(int* __restrict__ offs, const int* __restrict__ boffs,
                                int* __restrict__ cursor, int n, int total) {
    int i = blockIdx.x * 256 + threadIdx.x;
    if (i < n) {
        int o = offs[i] + boffs[blockIdx.x];
        offs[i] = o;
        cursor[i] = o;
    }
    if (i == 0) offs[n] = total;
}

__global__ void scatter_kernel(const int* __restrict__ src, const int* __restrict__ dst,
                               int* __restrict__ cursor, int* __restrict__ psrc, int E) {
    int e = blockIdx.x * 256 + threadIdx.x;
    if (e < E) {
        int p = atomicAdd(&cursor[dst[e]], 1);
        psrc[p] = src[e];
    }
}

// ---------------- A (row-major fp32) -> row-major bf16 hi/lo ----------------

__global__ __launch_bounds__(256) void splitA_rm(const float* __restrict__ A,
                                                 short* __restrict__ hi,
                                                 short* __restrict__ lo,
                                                 int total8) {
    int tid = blockIdx.x * 256 + threadIdx.x;
    if (tid >= total8) return;
    const float* p = A + (size_t)tid * 8;
    float4 x0 = ((const float4*)p)[0];
    float4 x1 = ((const float4*)p)[1];
    float xs[8] = {x0.x, x0.y, x0.z, x0.w, x1.x, x1.y, x1.z, x1.w};
    short8 hv, lv;
#pragma unroll
    for (int j = 0; j < 8; ++j) { short h, l; split1(xs[j], h, l); hv[j] = h; lv[j] = l; }
    ((short8*)hi)[tid] = hv;
    ((short8*)lo)[tid] = lv;
}

// ---------------- B -> hi/lo in MFMA B-fragment order ----------------
// offset (x8) = (c*(N/16)+g)*64 + lane ; lane=(n&15)+16*((k&31)>>3), j=k&7

__global__ __launch_bounds__(256) void splitB_kernel(const float* __restrict__ B,
                                                     short* __restrict__ hi,
                                                     short* __restrict__ lo,
                                                     int K, int N) {
    int tid = blockIdx.x * 256 + threadIdx.x;
    int NG = N >> 4;
    int total = (K >> 5) * NG * 64;
    if (tid >= total) return;
    int lane = tid & 63;
    int rc = tid >> 6;
    int g = rc % NG, c = rc / NG;
    int n = g * 16 + (lane & 15);
    int k = c * 32 + (lane >> 4) * 8;
    short8 hv, lv;
#pragma unroll
    for (int j = 0; j < 8; ++j) {
        float x = B[(size_t)(k + j) * N + n];
        short h = f2bf_rne(x);
        hv[j] = h;
        lv[j] = f2bf_rne(x - bf2f(h));
    }
    ((short8*)hi)[tid] = hv;
    ((short8*)lo)[tid] = lv;
}

// f16 hi/lo variant (for W1)
__global__ __launch_bounds__(256) void splitB_f16_kernel(const float* __restrict__ B,
                                                         _Float16* __restrict__ hi,
                                                         _Float16* __restrict__ lo,
                                                         int K, int N) {
    int tid = blockIdx.x * 256 + threadIdx.x;
    int NG = N >> 4;
    int total = (K >> 5) * NG * 64;
    if (tid >= total) return;
    int lane = tid & 63;
    int rc = tid >> 6;
    int g = rc % NG, c = rc / NG;
    int n = g * 16 + (lane & 15);
    int k = c * 32 + (lane >> 4) * 8;
    half8 hv, lv;
#pragma unroll
    for (int j = 0; j < 8; ++j) {
        float x = B[(size_t)(k + j) * N + n];
        _Float16 h = (_Float16)x;
        hv[j] = h;
        lv[j] = (_Float16)(x - (float)h);
    }
    ((half8*)hi)[tid] = hv;
    ((half8*)lo)[tid] = lv;
}

// permuted-W2 f16 hi/lo: Bp[h*256+k, c] = W2[k, h*256+c]; K=1024, N=256
__global__ __launch_bounds__(256) void splitB2_f16_kernel(const float* __restrict__ W2,
                                                          _Float16* __restrict__ hi,
                                                          _Float16* __restrict__ lo) {
    int tid = blockIdx.x * 256 + threadIdx.x;
    const int NG = 16;
    int total = (1024 >> 5) * NG * 64;   // 32768
    if (tid >= total) return;
    int lane = tid & 63;
    int rc = tid >> 6;
    int g = rc % NG, c = rc / NG;
    int n = g * 16 + (lane & 15);
    int kk = c * 32 + (lane >> 4) * 8;
    half8 hv, lv;
#pragma unroll
    for (int j = 0; j < 8; ++j) {
        int kg = kk + j;
        int h = kg >> 8, k = kg & 255;
        float x = W2[(size_t)k * 1024 + h * 256 + n];
        _Float16 hb = (_Float16)x;
        hv[j] = hb;
        lv[j] = (_Float16)(x - (float)hb);
    }
    ((half8*)hi)[tid] = hv;
    ((half8*)lo)[tid] = lv;
}

// ---------------- MFMA GEMMs, N=256, A via async LDS staging ----------------
// block: 64 rows x 256 cols; wave w owns rows [bm,bm+64) x cols [w*64,(w+1)*64).
// Fused elr epilogue (alv!=null): from fp32 acc, pre-quantization.

__device__ inline floatx4 mfma16(short8 a, short8 b, floatx4 c) {
    return __builtin_amdgcn_mfma_f32_16x16x32_bf16(a, b, c, 0, 0, 0);
}
__device__ inline floatx4 mfma16h(half8 a, half8 b, floatx4 c) {
    return __builtin_amdgcn_mfma_f32_16x16x32_f16(a, b, c, 0, 0, 0);
}

// bf16-pair A x bf16-pair B (3-MFMA). Used for layer 0 (A = fp32 feat split).
__global__ __launch_bounds__(256) void gemm_n256l(const short* __restrict__ Ahi,
                                                  const short* __restrict__ Alo,
                                                  const short* __restrict__ Bh,
                                                  const short* __restrict__ Bl,
                                                  _Float16* __restrict__ Cf,
                                                  const float* __restrict__ alv,
                                                  const float* __restrict__ arv,
                                                  float* __restrict__ elo,
                                                  float* __restrict__ ero,
                                                  int M, int K) {
    int KC = K >> 5;
    __shared__ short AhL[2048];   // 4 m-tiles x 64 lanes x 8 shorts = 4 KB
    __shared__ short AlL[2048];
    int t = threadIdx.x;
    int lane = t & 63;
    int w = t >> 6;
    int bm = blockIdx.x * 64;
    int g0 = w * 4;
    const short8* pBh = (const short8*)Bh;
    const short8* pBl = (const short8*)Bl;

    floatx4 acc[4][4] = {};

    int row = bm + (w << 4) + (lane & 15);
    if (row >= M) row = M - 1;                    // clamp: junk rows never stored
    const short* gh = Ahi + (size_t)row * K + ((lane >> 4) << 3);
    const short* gl = Alo + (size_t)row * K + ((lane >> 4) << 3);
    short* lh = AhL + w * 512;                    // wave-uniform LDS base
    short* ll = AlL + w * 512;

    for (int c = 0; c < KC; ++c) {
        load_lds16(gh + (size_t)c * 32, lh);
        load_lds16(gl + (size_t)c * 32, ll);
        short8 bh[4], bl[4];
#pragma unroll
        for (int g = 0; g < 4; ++g) {
            bh[g] = pBh[((size_t)c * 16 + g0 + g) * 64 + lane];
            bl[g] = pBl[((size_t)c * 16 + g0 + g) * 64 + lane];
        }
        __syncthreads();   // drains vmcnt: LDS staged, B regs ready
#pragma unroll
        for (int mt = 0; mt < 4; ++mt) {
            short8 ah = *(const short8*)(AhL + mt * 512 + lane * 8);
            short8 al = *(const short8*)(AlL + mt * 512 + lane * 8);
#pragma unroll
            for (int g = 0; g < 4; ++g) {
                acc[mt][g] = mfma16(ah, bh[g], acc[mt][g]);
                acc[mt][g] = mfma16(al, bh[g], acc[mt][g]);
                acc[mt][g] = mfma16(ah, bl[g], acc[mt][g]);
            }
        }
        __syncthreads();   // all LDS reads done before next overwrite
    }

    // C/D layout: col = lane&15, row = (lane>>4)*4 + reg
    int rowb = bm + (lane >> 4) * 4;
    int colb = w * 64 + (lane & 15);
#pragma unroll
    for (int mt = 0; mt < 4; ++mt) {
#pragma unroll
        for (int r = 0; r < 4; ++r) {
            int rr = rowb + mt * 16 + r;
            if (rr < M) {
#pragma unroll
                for (int g = 0; g < 4; ++g) {
                    Cf[(size_t)rr * 256 + colb + g * 16] = (_Float16)acc[mt][g][r];
                }
            }
        }
    }

    // fused elr: el[rr,w] = sum_f z[rr, w*64+f]*alv[w*64+f] (f = (lane&15)+g*16)
    if (alv) {
        float alr[4], arr_[4];
#pragma unroll
        for (int g = 0; g < 4; ++g) {
            int f = w * 64 + (lane & 15) + g * 16;
            alr[g] = alv[f];
            arr_[g] = arv[f];
        }
#pragma unroll
        for (int mt = 0; mt < 4; ++mt) {
#pragma unroll
            for (int r = 0; r < 4; ++r) {
                float se = acc[mt][0][r] * alr[0] + acc[mt][1][r] * alr[1] +
                           acc[mt][2][r] * alr[2] + acc[mt][3][r] * alr[3];
                float sr = acc[mt][0][r] * arr_[0] + acc[mt][1][r] * arr_[1] +
                           acc[mt][2][r] * arr_[2] + acc[mt][3][r] * arr_[3];
                se += __shfl_xor(se, 1); se += __shfl_xor(se, 2);
                se += __shfl_xor(se, 4); se += __shfl_xor(se, 8);
                sr += __shfl_xor(sr, 1); sr += __shfl_xor(sr, 2);
                sr += __shfl_xor(sr, 4); sr += __shfl_xor(sr, 8);
                int rr = rowb + mt * 16 + r;
                if ((lane & 15) == 0 && rr < M) {
                    elo[rr * 4 + w] = se;
                    ero[rr * 4 + w] = sr;
                }
            }
        }
    }
}

// single-f16 A x f16-pair B (2-MFMA). Used for L1 (A=h0 f16) and final
// (A=aggregated h1 f16, K=1024). Exactly one of C/Cf non-null.
__global__ __launch_bounds__(256) void gemm_f16_n256(const _Float16* __restrict__ A,
                                                     const _Float16* __restrict__ Bh,
                                                     const _Float16* __restrict__ Bl,
                                                     const float* __restrict__ bias4,
                                                     float* __restrict__ C,
                                                     _Float16* __restrict__ Cf,
                                                     const float* __restrict__ alv,
                                                     const float* __restrict__ arv,
                                                     float* __restrict__ elo,
                                                     float* __restrict__ ero,
                                                     int M, int K) {
    int KC = K >> 5;
    __shared__ _Float16 AL[2048];   // 4 m-tiles x 64 lanes x 8 halves = 4 KB
    int t = threadIdx.x;
    int lane = t & 63;
    int w = t >> 6;
    int bm = blockIdx.x * 64;
    int g0 = w * 4;
    const half8* pBh = (const half8*)Bh;
    const half8* pBl = (const half8*)Bl;

    floatx4 acc[4][4] = {};

    int row = bm + (w << 4) + (lane & 15);
    if (row >= M) row = M - 1;                    // clamp: junk rows never stored
    const _Float16* gA = A + (size_t)row * K + ((lane >> 4) << 3);
    _Float16* lA = AL + w * 512;                  // wave-uniform LDS base

    for (int c = 0; c < KC; ++c) {
        load_lds16(gA + (size_t)c * 32, lA);
        half8 bh[4], bl[4];
#pragma unroll
        for (int g = 0; g < 4; ++g) {
            bh[g] = pBh[((size_t)c * 16 + g0 + g) * 64 + lane];
            bl[g] = pBl[((size_t)c * 16 + g0 + g) * 64 + lane];
        }
        __syncthreads();   // drains vmcnt: LDS staged, B regs ready
#pragma unroll
        for (int mt = 0; mt < 4; ++mt) {
            half8 a = *(const half8*)(AL + mt * 512 + lane * 8);
#pragma unroll
            for (int g = 0; g < 4; ++g) {
                acc[mt][g] = mfma16h(a, bh[g], acc[mt][g]);
                acc[mt][g] = mfma16h(a, bl[g], acc[mt][g]);
            }
        }
        __syncthreads();   // all LDS reads done before next overwrite
    }

    // C/D layout: col = lane&15, row = (lane>>4)*4 + reg
    int rowb = bm + (lane >> 4) * 4;
    int colb = w * 64 + (lane & 15);
#pragma unroll
    for (int mt = 0; mt < 4; ++mt) {
#pragma unroll
        for (int r = 0; r < 4; ++r) {
            int rr = rowb + mt * 16 + r;
            if (rr < M) {
#pragma unroll
                for (int g = 0; g < 4; ++g) {
                    int col = colb + g * 16;
                    float v = acc[mt][g][r];
                    if (bias4) {
                        v = 0.25f * (v + bias4[col] + bias4[col + 256] +
                                     bias4[col + 512] + bias4[col + 768]);
                    }
                    if (Cf) Cf[(size_t)rr * 256 + col] = (_Float16)v;
                    else    C[(size_t)rr * 256 + col] = v;
                }
            }
        }
    }

    // fused elr from fp32 acc
    if (alv) {
        float alr[4], arr_[4];
#pragma unroll
        for (int g = 0; g < 4; ++g) {
            int f = w * 64 + (lane & 15) + g * 16;
            alr[g] = alv[f];
            arr_[g] = arv[f];
        }
#pragma unroll
        for (int mt = 0; mt < 4; ++mt) {
#pragma unroll
            for (int r = 0; r < 4; ++r) {
                float se = acc[mt][0][r] * alr[0] + acc[mt][1][r] * alr[1] +
                           acc[mt][2][r] * alr[2] + acc[mt][3][r] * alr[3];
                float sr = acc[mt][0][r] * arr_[0] + acc[mt][1][r] * arr_[1] +
                           acc[mt][2][r] * arr_[2] + acc[mt][3][r] * arr_[3];
                se += __shfl_xor(se, 1); se += __shfl_xor(se, 2);
                se += __shfl_xor(se, 4); se += __shfl_xor(se, 8);
                sr += __shfl_xor(sr, 1); sr += __shfl_xor(sr, 2);
                sr += __shfl_xor(sr, 4); sr += __shfl_xor(sr, 8);
                int rr = rowb + mt * 16 + r;
                if ((lane & 15) == 0 && rr < M) {
                    elo[rr * 4 + w] = se;
                    ero[rr * 4 + w] = sr;
                }
            }
        }
    }
}

// ---------------- attention score parts (layer 2) ----------------

// val[h*256+k] = sum_j W2[k,h*256+j]*al2[h,j] ; var likewise with ar2
__global__ __launch_bounds__(256) void proj_av_kernel(const float* __restrict__ W2,
                                                      const float* __restrict__ al2,
                                                      const float* __restrict__ ar2,
                                                      float* __restrict__ val,
                                                      float* __restrict__ var_) {
    int gid = blockIdx.x * 256 + threadIdx.x;
    int w = gid >> 6;
    int lane = threadIdx.x & 63;
    if (w >= 1024) return;
    int h = w >> 8, k = w & 255;
    const float* wrow = W2 + (size_t)k * 1024 + h * 256;
    const float* ap = al2 + h * 256;
    const float* rp = ar2 + h * 256;
    float sv = 0.f, sr = 0.f;
    for (int j = lane; j < 256; j += 64) {
        float x = wrow[j];
        sv += x * ap[j];
        sr += x * rp[j];
    }
#pragma unroll
    for (int off = 32; off > 0; off >>= 1) {
        sv += __shfl_down(sv, off);
        sr += __shfl_down(sr, off);
    }
    if (lane == 0) { val[w] = sv; var_[w] = sr; }
}

// el[n,h] = h1[n,:]·val[h,:], er likewise (h1 fp16)
__global__ __launch_bounds__(256) void elr2_kernel(const _Float16* __restrict__ h1,
                                                   const float* __restrict__ val,
                                                   const float* __restrict__ var_,
                                                   float* __restrict__ el,
                                                   float* __restrict__ er) {
    int gid = blockIdx.x * 256 + threadIdx.x;
    int w = gid >> 6;
    int lane = threadIdx.x & 63;
    if (w >= NN * 4) return;
    int n = w >> 2, h = w & 3;
    const _Float16* hr = h1 + (size_t)n * 256;
    const float* vp = val + h * 256;
    const float* rp = var_ + h * 256;
    float se = 0.f, sr = 0.f;
    for (int k = lane; k < 256; k += 64) {
        float x = (float)hr[k];
        se += x * vp[k];
        sr += x * rp[k];
    }
#pragma unroll
    for (int off = 32; off > 0; off >>= 1) {
        se += __shfl_down(se, off);
        sr += __shfl_down(sr, off);
    }
    if (lane == 0) { el[w] = se; er[w] = sr; }
}

// ---------------- aggregation (R0 loop bodies; fp16 arrays) ----------------

// layer 0: elu epilogue, writes single f16 h0 (consumed only by L1 f16 GEMM)

__global__ __launch_bounds__(256) void agg_bf_kernel(const _Float16* __restrict__ z,
                                                     const float* __restrict__ el,
                                                     const float* __restrict__ er,
                                                     const int* __restrict__ offs,
                                                     const int* __restrict__ psrc,
                                                     const float* __restrict__ bias,
                                                     _Float16* __restrict__ oh) {
    int n = blockIdx.x;
    int t = threadIdx.x;
    int h = t >> 6;
    __shared__ float p_lds[64][4];
    __shared__ int src_lds[64];
    __shared__ float den_lds[4];
    if (t < 4) den_lds[t] = 0.f;
    int beg = offs[n], end = offs[n + 1];
    float acc = 0.f;
    int e_local = t >> 2, hh = t & 3;
    float er_n = er[n * 4 + hh];
    for (int base = beg; base < end; base += 64) {
        int cnt = min(64, end - base);
        __syncthreads();
        if (e_local < cnt) {
            int s = psrc[base + e_local];
            if (hh == 0) src_lds[e_local] = s;
            float sc = el[s * 4 + hh] + er_n;
            sc = (sc > 0.f) ? sc : 0.2f * sc;
            float p = __expf(sc);
            p_lds[e_local][hh] = p;
            atomicAdd(&den_lds[hh], p);
        }
        __syncthreads();
        for (int e = 0; e < cnt; ++e) {
            acc += p_lds[e][h] * (float)z[(size_t)src_lds[e] * 256 + t];
        }
    }
    __syncthreads();
    float o = acc / fmaxf(den_lds[h], 1e-9f) + bias[t];
    o = (o > 0.f) ? o : (__expf(o) - 1.f);
    oh[(size_t)n * 256 + t] = (_Float16)o;
}

// layer 1: elu epilogue, fp16 out (consumed by elr2 + aggH gathers)

__global__ __launch_bounds__(256) void agg_kernel(const _Float16* __restrict__ z,
                                                  const float* __restrict__ el,
                                                  const float* __restrict__ er,
                                                  const int* __restrict__ offs,
                                                  const int* __restrict__ psrc,
                                                  const float* __restrict__ bias,
                                                  _Float16* __restrict__ out) {
    int n = blockIdx.x;
    int t = threadIdx.x;
    int h = t >> 6;
    __shared__ float p_lds[64][4];
    __shared__ int src_lds[64];
    __shared__ float den_lds[4];
    if (t < 4) den_lds[t] = 0.f;
    int beg = offs[n], end = offs[n + 1];
    float acc = 0.f;
    int e_local = t >> 2, hh = t & 3;
    float er_n = er[n * 4 + hh];
    for (int base = beg; base < end; base += 64) {
        int cnt = min(64, end - base);
        __syncthreads();
        if (e_local < cnt) {
            int s = psrc[base + e_local];
            if (hh == 0) src_lds[e_local] = s;
            float sc = el[s * 4 + hh] + er_n;
            sc = (sc > 0.f) ? sc : 0.2f * sc;
            float p = __expf(sc);
            p_lds[e_local][hh] = p;
            atomicAdd(&den_lds[hh], p);
        }
        __syncthreads();
        for (int e = 0; e < cnt; ++e) {
            acc += p_lds[e][h] * (float)z[(size_t)src_lds[e] * 256 + t];
        }
    }
    __syncthreads();
    float o = acc / fmaxf(den_lds[h], 1e-9f) + bias[t];
    o = (o > 0.f) ? o : (__expf(o) - 1.f);
    out[(size_t)n * 256 + t] = (_Float16)o;
}

// layer-2 aggregation of h1 (fp16) -> single f16 [N,1024] (consumed by fin GEMM)

__global__ __launch_bounds__(256) void aggH_f16_kernel(const _Float16* __restrict__ h1,
                                                       const float* __restrict__ el,
                                                       const float* __restrict__ er,
                                                       const int* __restrict__ offs,
                                                       const int* __restrict__ psrc,
                                                       _Float16* __restrict__ oA) {
    int n = blockIdx.x, t = threadIdx.x;
    __shared__ float p_lds[64][4];
    __shared__ int src_lds[64];
    __shared__ float den_lds[4];
    if (t < 4) den_lds[t] = 0.f;
    int beg = offs[n], end = offs[n + 1];
    float a0 = 0.f, a1 = 0.f, a2 = 0.f, a3 = 0.f;
    int e_local = t >> 2, hh = t & 3;
    float er_n = er[n * 4 + hh];
    for (int base = beg; base < end; base += 64) {
        int cnt = min(64, end - base);
        __syncthreads();
        if (e_local < cnt) {
            int s = psrc[base + e_local];
            if (hh == 0) src_lds[e_local] = s;
            float sc = el[s * 4 + hh] + er_n;
            sc = (sc > 0.f) ? sc : 0.2f * sc;
            float p = __expf(sc);
            p_lds[e_local][hh] = p;
            atomicAdd(&den_lds[hh], p);
        }
        __syncthreads();
        for (int e = 0; e < cnt; ++e) {
            float v = (float)h1[(size_t)src_lds[e] * 256 + t];
            a0 += p_lds[e][0] * v;
            a1 += p_lds[e][1] * v;
            a2 += p_lds[e][2] * v;
            a3 += p_lds[e][3] * v;
        }
    }
    __syncthreads();
    float vals[4];
    vals[0] = a0 / fmaxf(den_lds[0], 1e-9f);
    vals[1] = a1 / fmaxf(den_lds[1], 1e-9f);
    vals[2] = a2 / fmaxf(den_lds[2], 1e-9f);
    vals[3] = a3 / fmaxf(den_lds[3], 1e-9f);
    size_t base_o = (size_t)n * 1024 + t;
#pragma unroll
    for (int h = 0; h < 4; ++h) {
        oA[base_o + h * 256] = (_Float16)vals[h];
    }
}

// ---------------- launch ----------------

extern "C" void kernel_launch(void* const* d_in, const int* in_sizes, int n_in,
                              void* d_out, int out_size, void* d_ws, size_t ws_size,
                              hipStream_t stream) {
    const float* feat = (const float*)d_in[0];
    const float* W0 = (const float*)d_in[1];
    const float* al0 = (const float*)d_in[2];
    const float* ar0 = (const float*)d_in[3];
    const float* b0 = (const float*)d_in[4];
    const float* W1 = (const float*)d_in[5];
    const float* al1 = (const float*)d_in[6];
    const float* ar1 = (const float*)d_in[7];
    const float* b1 = (const float*)d_in[8];
    const float* W2 = (const float*)d_in[9];
    const float* al2 = (const float*)d_in[10];
    const float* ar2 = (const float*)d_in[11];
    const float* b2 = (const float*)d_in[12];
    const int* src = (const int*)d_in[13];
    const int* dst = (const int*)d_in[14];
    float* out = (float*)d_out;

    // ---- workspace layout (~262.5 MB), time-multiplexed big slots ----
    float* slotA = (float*)d_ws;
    _Float16* zh = (_Float16*)slotA;                      // [N,256] fp16 (z slot)
    short* feathi = (short*)(slotA + (size_t)NN * 256);   // 50000*128 shorts
    short* featlo = feathi + (size_t)NN * 128;
    _Float16* Af16 = (_Float16*)slotA;                    // [N,1024] f16 (layer 2)
    float* slotB = slotA + (size_t)NN * 1024;
    _Float16* h0f = (_Float16*)slotB;                     // [N,256] f16
    _Float16* h1h = (_Float16*)slotB;                     // [N,256] f16 (layer 2)
    float* el = slotB + (size_t)NN * 256;                 // 200000
    float* er = el + (size_t)NN * NH_HEADS;               // 200000
    int* deg = (int*)(er + (size_t)NN * NH_HEADS);        // 50000
    int* offs = deg + NN;                                 // 50001 (+1 pad)
    int* cursor = offs + NN + 2;                          // 50000
    int* bsums = cursor + NN;                             // 256
    int* boffs = bsums + 256;                             // 256
    int* psrc = boffs + 256;                              // 800000 (+2 pad)
    short* Bh = (short*)(psrc + NE + 2);                  // 262144 shorts / half8s
    short* Bl = Bh + 262144;                              // 262144 shorts
    float* val = (float*)(Bl + 262144);                   // 1024
    float* var_ = val + 1024;                             // 1024

    // ---- CSR build (by dst) ----
    hipMemsetAsync(deg, 0, NN * sizeof(int), stream);
    hist_kernel<<<(NE + 255) / 256, 256, 0, stream>>>(dst, deg, NE);
    int nb = (NN + 255) / 256;
    scan_block_kernel<<<nb, 256, 0, stream>>>(deg, offs, bsums, NN);
    scan_sums_kernel<<<1, 256, 0, stream>>>(bsums, boffs, nb);
    add_offs_kernel<<<nb, 256, 0, stream>>>(offs, boffs, cursor, NN, NE);
    scatter_kernel<<<(NE + 255) / 256, 256, 0, stream>>>(src, dst, cursor, psrc, NE);

    int mb64 = (NN + 63) / 64; // 782

    // ---- layer 0: 128 -> 4x64, elu (bf16-pair GEMM, elr fused; z fp16) ----
    splitA_rm<<<(NN * 128 / 8 + 255) / 256, 256, 0, stream>>>(feat, feathi, featlo, NN * 128 / 8);
    splitB_kernel<<<(4096 + 255) / 256, 256, 0, stream>>>(W0, Bh, Bl, 128, 256);
    gemm_n256l<<<mb64, 256, 0, stream>>>(feathi, featlo, Bh, Bl, zh,
                                         al0, ar0, el, er, NN, 128);
    agg_bf_kernel<<<NN, 256, 0, stream>>>(zh, el, er, offs, psrc, b0, h0f);

    // ---- layer 1: 256 -> 4x64, elu (f16 GEMM: A=h0 single f16; elr fused) ----
    splitB_f16_kernel<<<(8192 + 255) / 256, 256, 0, stream>>>(W1, (_Float16*)Bh,
                                                              (_Float16*)Bl, 256, 256);
    gemm_f16_n256<<<mb64, 256, 0, stream>>>(h0f, (const _Float16*)Bh, (const _Float16*)Bl,
                                            nullptr, nullptr, zh, al1, ar1, el, er,
                                            NN, 256);
    agg_kernel<<<NN, 256, 0, stream>>>(zh, el, er, offs, psrc, b1, h1h);

    // ---- layer 2: score from aggregated h1, then f16 K=1024 projection ----
    proj_av_kernel<<<256, 256, 0, stream>>>(W2, al2, ar2, val, var_);
    elr2_kernel<<<NN, 256, 0, stream>>>(h1h, val, var_, el, er);
    aggH_f16_kernel<<<NN, 256, 0, stream>>>(h1h, el, er, offs, psrc, Af16);
    splitB2_f16_kernel<<<(32768 + 255) / 256, 256, 0, stream>>>(W2, (_Float16*)Bh,
                                                                (_Float16*)Bl);
    gemm_f16_n256<<<mb64, 256, 0, stream>>>(Af16, (const _Float16*)Bh, (const _Float16*)Bl,
                                            b2, out, nullptr, nullptr, nullptr,
                                            nullptr, nullptr, NN, 1024);
}

// Round 13
// 615.155 us; speedup vs baseline: 1.3672x; 1.1961x over previous
//
#include <hip/hip_runtime.h>
#include <hip/hip_bf16.h>

// GAT: 3 layers. N=50000 nodes, E=800000 edges, H=4 heads.
// R13/R16: elr fused into GEMM epilogue; elr2 separate.
// R17: fp16 gather arrays -> 765us. R18: f16-native GEMMs (single-f16 A,
// f16-pair B, 2 MFMA) -> 735.8us. absmax pinned at 2^-11 throughout.
// R20: R18's counters showed fp16 gathers halved per-load width (128B/wave)
// -> in-flight bytes below Little's-law knee -> BW fell 4.3->2.7TB/s.
// Fix: 1-wave gather blocks, lane owns 4 cols via half4 (8B) loads =
// 512B/wave (full row). p-phase maps 1:1 onto 64 lanes (16 edges x 4
// heads), den via shfl_xor (single wave, no atomics), barriers ~free.
// agg_bf == agg now (both elu->f16): one kernel reused. GEMMs untouched.

#define NN 50000
#define NE 800000
#define NH_HEADS 4

typedef __attribute__((ext_vector_type(8))) short short8;
typedef __attribute__((ext_vector_type(8))) _Float16 half8;
typedef __attribute__((ext_vector_type(4))) _Float16 half4;
typedef __attribute__((ext_vector_type(4))) float floatx4;

__device__ inline float bf2f(short s) {
    union { unsigned u; float f; } v; v.u = ((unsigned)(unsigned short)s) << 16;
    return v.f;
}
__device__ inline short f2bf_rne(float x) {
    union { float f; unsigned u; } v; v.f = x;
    unsigned r = v.u + 0x7fff + ((v.u >> 16) & 1);
    return (short)(r >> 16);
}
// truncation hi/lo split: hi = trunc16(x), lo = trunc16(x - hi)
__device__ inline void split1(float x, short& h, short& l) {
    union { float f; unsigned u; } v; v.f = x;
    h = (short)(v.u >> 16);
    union { float f; unsigned u; } rv; rv.f = v.f - bf2f(h);
    l = (short)(rv.u >> 16);
}

// async 16B/lane global->LDS; lds base must be wave-uniform (dest = base + lane*16)
__device__ inline void load_lds16(const void* g, void* l) {
    __builtin_amdgcn_global_load_lds(
        (const __attribute__((address_space(1))) void*)g,
        (__attribute__((address_space(3))) void*)l, 16, 0, 0);
}

// ---------------- CSR build ----------------

__global__ void hist_kernel(const int* __restrict__ dst, int* __restrict__ deg, int E) {
    int e = blockIdx.x * 256 + threadIdx.x;
    if (e < E) atomicAdd(&deg[dst[e]], 1);
}

__global__ void scan_block_kernel(const int* __restrict__ deg, int* __restrict__ offs,
                                  int* __restrict__ bsums, int n) {
    __shared__ int s[256];
    int tid = threadIdx.x;
    int i = blockIdx.x * 256 + tid;
    int v = (i < n) ? deg[i] : 0;
    s[tid] = v;
    __syncthreads();
    for (int off = 1; off < 256; off <<= 1) {
        int x = (tid >= off) ? s[tid - off] : 0;
        __syncthreads();
        s[tid] += x;
        __syncthreads();
    }
    if (i < n) offs[i] = s[tid] - v;
    if (tid == 255) bsums[blockIdx.x] = s[255];
}

__global__ void scan_sums_kernel(const int* __restrict__ bsums, int* __restrict__ boffs, int nb) {
    __shared__ int s[256];
    int tid = threadIdx.x;
    int v = (tid < nb) ? bsums[tid] : 0;
    s[tid] = v;
    __syncthreads();
    for (int off = 1; off < 256; off <<= 1) {
        int x = (tid >= off) ? s[tid - off] : 0;
        __syncthreads();
        s[tid] += x;
        __syncthreads();
    }
    boffs[tid] = s[tid] - v;
}

__global__ void add_offs_kernel(int* __restrict__ offs, const int* __restrict__ boffs,
                                int* __restrict__ cursor, int n, int total) {
    int i = blockIdx.x * 256 + threadIdx.x;
    if (i < n) {
        int o = offs[i] + boffs[blockIdx.x];
        offs[i] = o;
        cursor[i] = o;
    }
    if (i == 0) offs[n] = total;
}

__global__ void scatter_kernel(const int* __restrict__ src, const int* __restrict__ dst,
                               int* __restrict__ cursor, int* __restrict__ psrc, int E) {
    int e = blockIdx.x * 256 + threadIdx.x;
    if (e < E) {
        int p = atomicAdd(&cursor[dst[e]], 1);
        psrc[p] = src[e];
    }
}

// ---------------- A (row-major fp32) -> row-major bf16 hi/lo ----------------

__global__ __launch_bounds__(256) void splitA_rm(const float* __restrict__ A,
                                                 short* __restrict__ hi,
                                                 short* __restrict__ lo,
                                                 int total8) {
    int tid = blockIdx.x * 256 + threadIdx.x;
    if (tid >= total8) return;
    const float* p = A + (size_t)tid * 8;
    float4 x0 = ((const float4*)p)[0];
    float4 x1 = ((const float4*)p)[1];
    float xs[8] = {x0.x, x0.y, x0.z, x0.w, x1.x, x1.y, x1.z, x1.w};
    short8 hv, lv;
#pragma unroll
    for (int j = 0; j < 8; ++j) { short h, l; split1(xs[j], h, l); hv[j] = h; lv[j] = l; }
    ((short8*)hi)[tid] = hv;
    ((short8*)lo)[tid] = lv;
}

// ---------------- B -> hi/lo in MFMA B-fragment order ----------------
// offset (x8) = (c*(N/16)+g)*64 + lane ; lane=(n&15)+16*((k&31)>>3), j=k&7

__global__ __launch_bounds__(256) void splitB_kernel(const float* __restrict__ B,
                                                     short* __restrict__ hi,
                                                     short* __restrict__ lo,
                                                     int K, int N) {
    int tid = blockIdx.x * 256 + threadIdx.x;
    int NG = N >> 4;
    int total = (K >> 5) * NG * 64;
    if (tid >= total) return;
    int lane = tid & 63;
    int rc = tid >> 6;
    int g = rc % NG, c = rc / NG;
    int n = g * 16 + (lane & 15);
    int k = c * 32 + (lane >> 4) * 8;
    short8 hv, lv;
#pragma unroll
    for (int j = 0; j < 8; ++j) {
        float x = B[(size_t)(k + j) * N + n];
        short h = f2bf_rne(x);
        hv[j] = h;
        lv[j] = f2bf_rne(x - bf2f(h));
    }
    ((short8*)hi)[tid] = hv;
    ((short8*)lo)[tid] = lv;
}

// f16 hi/lo variant (for W1)
__global__ __launch_bounds__(256) void splitB_f16_kernel(const float* __restrict__ B,
                                                         _Float16* __restrict__ hi,
                                                         _Float16* __restrict__ lo,
                                                         int K, int N) {
    int tid = blockIdx.x * 256 + threadIdx.x;
    int NG = N >> 4;
    int total = (K >> 5) * NG * 64;
    if (tid >= total) return;
    int lane = tid & 63;
    int rc = tid >> 6;
    int g = rc % NG, c = rc / NG;
    int n = g * 16 + (lane & 15);
    int k = c * 32 + (lane >> 4) * 8;
    half8 hv, lv;
#pragma unroll
    for (int j = 0; j < 8; ++j) {
        float x = B[(size_t)(k + j) * N + n];
        _Float16 h = (_Float16)x;
        hv[j] = h;
        lv[j] = (_Float16)(x - (float)h);
    }
    ((half8*)hi)[tid] = hv;
    ((half8*)lo)[tid] = lv;
}

// permuted-W2 f16 hi/lo: Bp[h*256+k, c] = W2[k, h*256+c]; K=1024, N=256
__global__ __launch_bounds__(256) void splitB2_f16_kernel(const float* __restrict__ W2,
                                                          _Float16* __restrict__ hi,
                                                          _Float16* __restrict__ lo) {
    int tid = blockIdx.x * 256 + threadIdx.x;
    const int NG = 16;
    int total = (1024 >> 5) * NG * 64;   // 32768
    if (tid >= total) return;
    int lane = tid & 63;
    int rc = tid >> 6;
    int g = rc % NG, c = rc / NG;
    int n = g * 16 + (lane & 15);
    int kk = c * 32 + (lane >> 4) * 8;
    half8 hv, lv;
#pragma unroll
    for (int j = 0; j < 8; ++j) {
        int kg = kk + j;
        int h = kg >> 8, k = kg & 255;
        float x = W2[(size_t)k * 1024 + h * 256 + n];
        _Float16 hb = (_Float16)x;
        hv[j] = hb;
        lv[j] = (_Float16)(x - (float)hb);
    }
    ((half8*)hi)[tid] = hv;
    ((half8*)lo)[tid] = lv;
}

// ---------------- MFMA GEMMs, N=256, A via async LDS staging ----------------
// block: 64 rows x 256 cols; wave w owns rows [bm,bm+64) x cols [w*64,(w+1)*64).
// Fused elr epilogue (alv!=null): from fp32 acc, pre-quantization.

__device__ inline floatx4 mfma16(short8 a, short8 b, floatx4 c) {
    return __builtin_amdgcn_mfma_f32_16x16x32_bf16(a, b, c, 0, 0, 0);
}
__device__ inline floatx4 mfma16h(half8 a, half8 b, floatx4 c) {
    return __builtin_amdgcn_mfma_f32_16x16x32_f16(a, b, c, 0, 0, 0);
}

// bf16-pair A x bf16-pair B (3-MFMA). Used for layer 0 (A = fp32 feat split).
__global__ __launch_bounds__(256) void gemm_n256l(const short* __restrict__ Ahi,
                                                  const short* __restrict__ Alo,
                                                  const short* __restrict__ Bh,
                                                  const short* __restrict__ Bl,
                                                  _Float16* __restrict__ Cf,
                                                  const float* __restrict__ alv,
                                                  const float* __restrict__ arv,
                                                  float* __restrict__ elo,
                                                  float* __restrict__ ero,
                                                  int M, int K) {
    int KC = K >> 5;
    __shared__ short AhL[2048];   // 4 m-tiles x 64 lanes x 8 shorts = 4 KB
    __shared__ short AlL[2048];
    int t = threadIdx.x;
    int lane = t & 63;
    int w = t >> 6;
    int bm = blockIdx.x * 64;
    int g0 = w * 4;
    const short8* pBh = (const short8*)Bh;
    const short8* pBl = (const short8*)Bl;

    floatx4 acc[4][4] = {};

    int row = bm + (w << 4) + (lane & 15);
    if (row >= M) row = M - 1;                    // clamp: junk rows never stored
    const short* gh = Ahi + (size_t)row * K + ((lane >> 4) << 3);
    const short* gl = Alo + (size_t)row * K + ((lane >> 4) << 3);
    short* lh = AhL + w * 512;                    // wave-uniform LDS base
    short* ll = AlL + w * 512;

    for (int c = 0; c < KC; ++c) {
        load_lds16(gh + (size_t)c * 32, lh);
        load_lds16(gl + (size_t)c * 32, ll);
        short8 bh[4], bl[4];
#pragma unroll
        for (int g = 0; g < 4; ++g) {
            bh[g] = pBh[((size_t)c * 16 + g0 + g) * 64 + lane];
            bl[g] = pBl[((size_t)c * 16 + g0 + g) * 64 + lane];
        }
        __syncthreads();   // drains vmcnt: LDS staged, B regs ready
#pragma unroll
        for (int mt = 0; mt < 4; ++mt) {
            short8 ah = *(const short8*)(AhL + mt * 512 + lane * 8);
            short8 al = *(const short8*)(AlL + mt * 512 + lane * 8);
#pragma unroll
            for (int g = 0; g < 4; ++g) {
                acc[mt][g] = mfma16(ah, bh[g], acc[mt][g]);
                acc[mt][g] = mfma16(al, bh[g], acc[mt][g]);
                acc[mt][g] = mfma16(ah, bl[g], acc[mt][g]);
            }
        }
        __syncthreads();   // all LDS reads done before next overwrite
    }

    // C/D layout: col = lane&15, row = (lane>>4)*4 + reg
    int rowb = bm + (lane >> 4) * 4;
    int colb = w * 64 + (lane & 15);
#pragma unroll
    for (int mt = 0; mt < 4; ++mt) {
#pragma unroll
        for (int r = 0; r < 4; ++r) {
            int rr = rowb + mt * 16 + r;
            if (rr < M) {
#pragma unroll
                for (int g = 0; g < 4; ++g) {
                    Cf[(size_t)rr * 256 + colb + g * 16] = (_Float16)acc[mt][g][r];
                }
            }
        }
    }

    // fused elr: el[rr,w] = sum_f z[rr, w*64+f]*alv[w*64+f] (f = (lane&15)+g*16)
    if (alv) {
        float alr[4], arr_[4];
#pragma unroll
        for (int g = 0; g < 4; ++g) {
            int f = w * 64 + (lane & 15) + g * 16;
            alr[g] = alv[f];
            arr_[g] = arv[f];
        }
#pragma unroll
        for (int mt = 0; mt < 4; ++mt) {
#pragma unroll
            for (int r = 0; r < 4; ++r) {
                float se = acc[mt][0][r] * alr[0] + acc[mt][1][r] * alr[1] +
                           acc[mt][2][r] * alr[2] + acc[mt][3][r] * alr[3];
                float sr = acc[mt][0][r] * arr_[0] + acc[mt][1][r] * arr_[1] +
                           acc[mt][2][r] * arr_[2] + acc[mt][3][r] * arr_[3];
                se += __shfl_xor(se, 1); se += __shfl_xor(se, 2);
                se += __shfl_xor(se, 4); se += __shfl_xor(se, 8);
                sr += __shfl_xor(sr, 1); sr += __shfl_xor(sr, 2);
                sr += __shfl_xor(sr, 4); sr += __shfl_xor(sr, 8);
                int rr = rowb + mt * 16 + r;
                if ((lane & 15) == 0 && rr < M) {
                    elo[rr * 4 + w] = se;
                    ero[rr * 4 + w] = sr;
                }
            }
        }
    }
}

// single-f16 A x f16-pair B (2-MFMA). Used for L1 (A=h0 f16) and final
// (A=aggregated h1 f16, K=1024). Exactly one of C/Cf non-null.
__global__ __launch_bounds__(256) void gemm_f16_n256(const _Float16* __restrict__ A,
                                                     const _Float16* __restrict__ Bh,
                                                     const _Float16* __restrict__ Bl,
                                                     const float* __restrict__ bias4,
                                                     float* __restrict__ C,
                                                     _Float16* __restrict__ Cf,
                                                     const float* __restrict__ alv,
                                                     const float* __restrict__ arv,
                                                     float* __restrict__ elo,
                                                     float* __restrict__ ero,
                                                     int M, int K) {
    int KC = K >> 5;
    __shared__ _Float16 AL[2048];   // 4 m-tiles x 64 lanes x 8 halves = 4 KB
    int t = threadIdx.x;
    int lane = t & 63;
    int w = t >> 6;
    int bm = blockIdx.x * 64;
    int g0 = w * 4;
    const half8* pBh = (const half8*)Bh;
    const half8* pBl = (const half8*)Bl;

    floatx4 acc[4][4] = {};

    int row = bm + (w << 4) + (lane & 15);
    if (row >= M) row = M - 1;                    // clamp: junk rows never stored
    const _Float16* gA = A + (size_t)row * K + ((lane >> 4) << 3);
    _Float16* lA = AL + w * 512;                  // wave-uniform LDS base

    for (int c = 0; c < KC; ++c) {
        load_lds16(gA + (size_t)c * 32, lA);
        half8 bh[4], bl[4];
#pragma unroll
        for (int g = 0; g < 4; ++g) {
            bh[g] = pBh[((size_t)c * 16 + g0 + g) * 64 + lane];
            bl[g] = pBl[((size_t)c * 16 + g0 + g) * 64 + lane];
        }
        __syncthreads();   // drains vmcnt: LDS staged, B regs ready
#pragma unroll
        for (int mt = 0; mt < 4; ++mt) {
            half8 a = *(const half8*)(AL + mt * 512 + lane * 8);
#pragma unroll
            for (int g = 0; g < 4; ++g) {
                acc[mt][g] = mfma16h(a, bh[g], acc[mt][g]);
                acc[mt][g] = mfma16h(a, bl[g], acc[mt][g]);
            }
        }
        __syncthreads();   // all LDS reads done before next overwrite
    }

    // C/D layout: col = lane&15, row = (lane>>4)*4 + reg
    int rowb = bm + (lane >> 4) * 4;
    int colb = w * 64 + (lane & 15);
#pragma unroll
    for (int mt = 0; mt < 4; ++mt) {
#pragma unroll
        for (int r = 0; r < 4; ++r) {
            int rr = rowb + mt * 16 + r;
            if (rr < M) {
#pragma unroll
                for (int g = 0; g < 4; ++g) {
                    int col = colb + g * 16;
                    float v = acc[mt][g][r];
                    if (bias4) {
                        v = 0.25f * (v + bias4[col] + bias4[col + 256] +
                                     bias4[col + 512] + bias4[col + 768]);
                    }
                    if (Cf) Cf[(size_t)rr * 256 + col] = (_Float16)v;
                    else    C[(size_t)rr * 256 + col] = v;
                }
            }
        }
    }

    // fused elr from fp32 acc
    if (alv) {
        float alr[4], arr_[4];
#pragma unroll
        for (int g = 0; g < 4; ++g) {
            int f = w * 64 + (lane & 15) + g * 16;
            alr[g] = alv[f];
            arr_[g] = arv[f];
        }
#pragma unroll
        for (int mt = 0; mt < 4; ++mt) {
#pragma unroll
            for (int r = 0; r < 4; ++r) {
                float se = acc[mt][0][r] * alr[0] + acc[mt][1][r] * alr[1] +
                           acc[mt][2][r] * alr[2] + acc[mt][3][r] * alr[3];
                float sr = acc[mt][0][r] * arr_[0] + acc[mt][1][r] * arr_[1] +
                           acc[mt][2][r] * arr_[2] + acc[mt][3][r] * arr_[3];
                se += __shfl_xor(se, 1); se += __shfl_xor(se, 2);
                se += __shfl_xor(se, 4); se += __shfl_xor(se, 8);
                sr += __shfl_xor(sr, 1); sr += __shfl_xor(sr, 2);
                sr += __shfl_xor(sr, 4); sr += __shfl_xor(sr, 8);
                int rr = rowb + mt * 16 + r;
                if ((lane & 15) == 0 && rr < M) {
                    elo[rr * 4 + w] = se;
                    ero[rr * 4 + w] = sr;
                }
            }
        }
    }
}

// ---------------- attention score parts (layer 2) ----------------

// val[h*256+k] = sum_j W2[k,h*256+j]*al2[h,j] ; var likewise with ar2
__global__ __launch_bounds__(256) void proj_av_kernel(const float* __restrict__ W2,
                                                      const float* __restrict__ al2,
                                                      const float* __restrict__ ar2,
                                                      float* __restrict__ val,
                                                      float* __restrict__ var_) {
    int gid = blockIdx.x * 256 + threadIdx.x;
    int w = gid >> 6;
    int lane = threadIdx.x & 63;
    if (w >= 1024) return;
    int h = w >> 8, k = w & 255;
    const float* wrow = W2 + (size_t)k * 1024 + h * 256;
    const float* ap = al2 + h * 256;
    const float* rp = ar2 + h * 256;
    float sv = 0.f, sr = 0.f;
    for (int j = lane; j < 256; j += 64) {
        float x = wrow[j];
        sv += x * ap[j];
        sr += x * rp[j];
    }
#pragma unroll
    for (int off = 32; off > 0; off >>= 1) {
        sv += __shfl_down(sv, off);
        sr += __shfl_down(sr, off);
    }
    if (lane == 0) { val[w] = sv; var_[w] = sr; }
}

// el[n,h] = h1[n,:]·val[h,:], er likewise (h1 fp16)
__global__ __launch_bounds__(256) void elr2_kernel(const _Float16* __restrict__ h1,
                                                   const float* __restrict__ val,
                                                   const float* __restrict__ var_,
                                                   float* __restrict__ el,
                                                   float* __restrict__ er) {
    int gid = blockIdx.x * 256 + threadIdx.x;
    int w = gid >> 6;
    int lane = threadIdx.x & 63;
    if (w >= NN * 4) return;
    int n = w >> 2, h = w & 3;
    const _Float16* hr = h1 + (size_t)n * 256;
    const float* vp = val + h * 256;
    const float* rp = var_ + h * 256;
    float se = 0.f, sr = 0.f;
    for (int k = lane; k < 256; k += 64) {
        float x = (float)hr[k];
        se += x * vp[k];
        sr += x * rp[k];
    }
#pragma unroll
    for (int off = 32; off > 0; off >>= 1) {
        se += __shfl_down(se, off);
        sr += __shfl_down(sr, off);
    }
    if (lane == 0) { el[w] = se; er[w] = sr; }
}

// ---------------- aggregation: 1-wave blocks, half4 loads ----------------
// Block = 64 lanes = one node. Lane l owns cols 4l..4l+3 (head h = l>>4).
// p-phase: chunk = 16 edges x 4 heads = 64 lanes (e_local = l>>2, hh = l&3);
// den via shfl_xor strides {4,8,16,32} (preserves hh groups), lanes 0..3
// accumulate den_lds across chunks (single wave: program order, no atomics).
// Gather: one half4 (8B) load per edge per lane = 512B/wave (full row).

// z-gather (layers 0 & 1): elu epilogue, f16 out [N,256].
__global__ __launch_bounds__(64) void agg_z64_kernel(const _Float16* __restrict__ z,
                                                     const float* __restrict__ el,
                                                     const float* __restrict__ er,
                                                     const int* __restrict__ offs,
                                                     const int* __restrict__ psrc,
                                                     const float* __restrict__ bias,
                                                     _Float16* __restrict__ out) {
    int n = blockIdx.x;
    int l = threadIdx.x;
    __shared__ float p_lds[16][4];
    __shared__ int src_lds[16];
    __shared__ float den_lds[4];
    if (l < 4) den_lds[l] = 0.f;
    int e_local = l >> 2, hh = l & 3;
    int h = l >> 4;
    float er_n = er[n * 4 + hh];
    int beg = offs[n], end = offs[n + 1];
    float a0 = 0.f, a1 = 0.f, a2 = 0.f, a3 = 0.f;
    for (int base = beg; base < end; base += 16) {
        int cnt = min(16, end - base);
        __syncthreads();
        float p = 0.f;
        if (e_local < cnt) {
            int s = psrc[base + e_local];
            if (hh == 0) src_lds[e_local] = s;
            float sc = el[s * 4 + hh] + er_n;
            sc = (sc > 0.f) ? sc : 0.2f * sc;
            p = __expf(sc);
            p_lds[e_local][hh] = p;
        }
        float d = p;
        d += __shfl_xor(d, 4);  d += __shfl_xor(d, 8);
        d += __shfl_xor(d, 16); d += __shfl_xor(d, 32);
        if (l < 4) den_lds[l] += d;
        __syncthreads();
        for (int e = 0; e < cnt; ++e) {
            half4 v = *(const half4*)(z + (size_t)src_lds[e] * 256 + (l << 2));
            float pe = p_lds[e][h];
            a0 += pe * (float)v[0];
            a1 += pe * (float)v[1];
            a2 += pe * (float)v[2];
            a3 += pe * (float)v[3];
        }
    }
    __syncthreads();
    float rd = 1.f / fmaxf(den_lds[h], 1e-9f);
    float vals[4] = {a0, a1, a2, a3};
    half4 o;
#pragma unroll
    for (int j = 0; j < 4; ++j) {
        float x = vals[j] * rd + bias[(l << 2) + j];
        x = (x > 0.f) ? x : (__expf(x) - 1.f);
        o[j] = (_Float16)x;
    }
    *(half4*)(out + (size_t)n * 256 + (l << 2)) = o;
}

// layer-2 aggregation of h1 (fp16) -> single f16 [N,1024] (all 4 heads/lane).
__global__ __launch_bounds__(64) void aggH_64_kernel(const _Float16* __restrict__ h1,
                                                     const float* __restrict__ el,
                                                     const float* __restrict__ er,
                                                     const int* __restrict__ offs,
                                                     const int* __restrict__ psrc,
                                                     _Float16* __restrict__ oA) {
    int n = blockIdx.x;
    int l = threadIdx.x;
    __shared__ __align__(16) float p_lds[16][4];
    __shared__ int src_lds[16];
    __shared__ float den_lds[4];
    if (l < 4) den_lds[l] = 0.f;
    int e_local = l >> 2, hh = l & 3;
    float er_n = er[n * 4 + hh];
    int beg = offs[n], end = offs[n + 1];
    float acc[4][4] = {};   // [head][colj]
    for (int base = beg; base < end; base += 16) {
        int cnt = min(16, end - base);
        __syncthreads();
        float p = 0.f;
        if (e_local < cnt) {
            int s = psrc[base + e_local];
            if (hh == 0) src_lds[e_local] = s;
            float sc = el[s * 4 + hh] + er_n;
            sc = (sc > 0.f) ? sc : 0.2f * sc;
            p = __expf(sc);
            p_lds[e_local][hh] = p;
        }
        float d = p;
        d += __shfl_xor(d, 4);  d += __shfl_xor(d, 8);
        d += __shfl_xor(d, 16); d += __shfl_xor(d, 32);
        if (l < 4) den_lds[l] += d;
        __syncthreads();
        for (int e = 0; e < cnt; ++e) {
            half4 v = *(const half4*)(h1 + (size_t)src_lds[e] * 256 + (l << 2));
            float vf0 = (float)v[0], vf1 = (float)v[1];
            float vf2 = (float)v[2], vf3 = (float)v[3];
            floatx4 pv = *(const floatx4*)&p_lds[e][0];
#pragma unroll
            for (int hd = 0; hd < 4; ++hd) {
                acc[hd][0] += pv[hd] * vf0;
                acc[hd][1] += pv[hd] * vf1;
                acc[hd][2] += pv[hd] * vf2;
                acc[hd][3] += pv[hd] * vf3;
            }
        }
    }
    __syncthreads();
    size_t base_o = (size_t)n * 1024 + (l << 2);
#pragma unroll
    for (int hd = 0; hd < 4; ++hd) {
        float rd = 1.f / fmaxf(den_lds[hd], 1e-9f);
        half4 o;
#pragma unroll
        for (int j = 0; j < 4; ++j) o[j] = (_Float16)(acc[hd][j] * rd);
        *(half4*)(oA + base_o + hd * 256) = o;
    }
}

// ---------------- launch ----------------

extern "C" void kernel_launch(void* const* d_in, const int* in_sizes, int n_in,
                              void* d_out, int out_size, void* d_ws, size_t ws_size,
                              hipStream_t stream) {
    const float* feat = (const float*)d_in[0];
    const float* W0 = (const float*)d_in[1];
    const float* al0 = (const float*)d_in[2];
    const float* ar0 = (const float*)d_in[3];
    const float* b0 = (const float*)d_in[4];
    const float* W1 = (const float*)d_in[5];
    const float* al1 = (const float*)d_in[6];
    const float* ar1 = (const float*)d_in[7];
    const float* b1 = (const float*)d_in[8];
    const float* W2 = (const float*)d_in[9];
    const float* al2 = (const float*)d_in[10];
    const float* ar2 = (const float*)d_in[11];
    const float* b2 = (const float*)d_in[12];
    const int* src = (const int*)d_in[13];
    const int* dst = (const int*)d_in[14];
    float* out = (float*)d_out;

    // ---- workspace layout (~262.5 MB), time-multiplexed big slots ----
    float* slotA = (float*)d_ws;
    _Float16* zh = (_Float16*)slotA;                      // [N,256] fp16 (z slot)
    short* feathi = (short*)(slotA + (size_t)NN * 256);   // 50000*128 shorts
    short* featlo = feathi + (size_t)NN * 128;
    _Float16* Af16 = (_Float16*)slotA;                    // [N,1024] f16 (layer 2)
    float* slotB = slotA + (size_t)NN * 1024;
    _Float16* h0f = (_Float16*)slotB;                     // [N,256] f16
    _Float16* h1h = (_Float16*)slotB;                     // [N,256] f16 (layer 2)
    float* el = slotB + (size_t)NN * 256;                 // 200000
    float* er = el + (size_t)NN * NH_HEADS;               // 200000
    int* deg = (int*)(er + (size_t)NN * NH_HEADS);        // 50000
    int* offs = deg + NN;                                 // 50001 (+1 pad)
    int* cursor = offs + NN + 2;                          // 50000
    int* bsums = cursor + NN;                             // 256
    int* boffs = bsums + 256;                             // 256
    int* psrc = boffs + 256;                              // 800000 (+2 pad)
    short* Bh = (short*)(psrc + NE + 2);                  // 262144 shorts / half8s
    short* Bl = Bh + 262144;                              // 262144 shorts
    float* val = (float*)(Bl + 262144);                   // 1024
    float* var_ = val + 1024;                             // 1024

    // ---- CSR build (by dst) ----
    hipMemsetAsync(deg, 0, NN * sizeof(int), stream);
    hist_kernel<<<(NE + 255) / 256, 256, 0, stream>>>(dst, deg, NE);
    int nb = (NN + 255) / 256;
    scan_block_kernel<<<nb, 256, 0, stream>>>(deg, offs, bsums, NN);
    scan_sums_kernel<<<1, 256, 0, stream>>>(bsums, boffs, nb);
    add_offs_kernel<<<nb, 256, 0, stream>>>(offs, boffs, cursor, NN, NE);
    scatter_kernel<<<(NE + 255) / 256, 256, 0, stream>>>(src, dst, cursor, psrc, NE);

    int mb64 = (NN + 63) / 64; // 782

    // ---- layer 0: 128 -> 4x64, elu (bf16-pair GEMM, elr fused; z fp16) ----
    splitA_rm<<<(NN * 128 / 8 + 255) / 256, 256, 0, stream>>>(feat, feathi, featlo, NN * 128 / 8);
    splitB_kernel<<<(4096 + 255) / 256, 256, 0, stream>>>(W0, Bh, Bl, 128, 256);
    gemm_n256l<<<mb64, 256, 0, stream>>>(feathi, featlo, Bh, Bl, zh,
                                         al0, ar0, el, er, NN, 128);
    agg_z64_kernel<<<NN, 64, 0, stream>>>(zh, el, er, offs, psrc, b0, h0f);

    // ---- layer 1: 256 -> 4x64, elu (f16 GEMM: A=h0 single f16; elr fused) ----
    splitB_f16_kernel<<<(8192 + 255) / 256, 256, 0, stream>>>(W1, (_Float16*)Bh,
                                                              (_Float16*)Bl, 256, 256);
    gemm_f16_n256<<<mb64, 256, 0, stream>>>(h0f, (const _Float16*)Bh, (const _Float16*)Bl,
                                            nullptr, nullptr, zh, al1, ar1, el, er,
                                            NN, 256);
    agg_z64_kernel<<<NN, 64, 0, stream>>>(zh, el, er, offs, psrc, b1, h1h);

    // ---- layer 2: score from aggregated h1, then f16 K=1024 projection ----
    proj_av_kernel<<<256, 256, 0, stream>>>(W2, al2, ar2, val, var_);
    elr2_kernel<<<NN, 256, 0, stream>>>(h1h, val, var_, el, er);
    aggH_64_kernel<<<NN, 64, 0, stream>>>(h1h, el, er, offs, psrc, Af16);
    splitB2_f16_kernel<<<(32768 + 255) / 256, 256, 0, stream>>>(W2, (_Float16*)Bh,
                                                                (_Float16*)Bl);
    gemm_f16_n256<<<mb64, 256, 0, stream>>>(Af16, (const _Float16*)Bh, (const _Float16*)Bl,
                                            b2, out, nullptr, nullptr, nullptr,
                                            nullptr, nullptr, NN, 1024);
}

// Round 14
// 592.650 us; speedup vs baseline: 1.4192x; 1.0380x over previous
//
#include <hip/hip_runtime.h>
#include <hip/hip_bf16.h>

// GAT: 3 layers. N=50000 nodes, E=800000 edges, H=4 heads.
// R13/R16: elr fused into GEMM epilogue; elr2 separate.
// R17: fp16 gather arrays -> 765us. R18: f16-native GEMMs -> 735.8us.
// R20: 1-wave gather blocks, half4 (8B) loads = full 512B row/wave ->
// 615.2us; gathers out of top-5. absmax pinned at 2^-11 since R0.
// R21: final K=1024 GEMM was the top cost (105us, latency/barrier-bound,
// B-frag stream = 128B/lane/chunk). The final output is the HEAD-MEAN
// (epilogue x0.25), so W2's f16 quantization error is scaled by 0.25
// (~1.5e-4 rms, << 4.9e-4 existing): drop the B-lo term for the final
// projection only -> half the MFMAs + half the B traffic. L0/L1 keep
// full hi/lo pairs. splitB2 writes hi only.

#define NN 50000
#define NE 800000
#define NH_HEADS 4

typedef __attribute__((ext_vector_type(8))) short short8;
typedef __attribute__((ext_vector_type(8))) _Float16 half8;
typedef __attribute__((ext_vector_type(4))) _Float16 half4;
typedef __attribute__((ext_vector_type(4))) float floatx4;

__device__ inline float bf2f(short s) {
    union { unsigned u; float f; } v; v.u = ((unsigned)(unsigned short)s) << 16;
    return v.f;
}
__device__ inline short f2bf_rne(float x) {
    union { float f; unsigned u; } v; v.f = x;
    unsigned r = v.u + 0x7fff + ((v.u >> 16) & 1);
    return (short)(r >> 16);
}
// truncation hi/lo split: hi = trunc16(x), lo = trunc16(x - hi)
__device__ inline void split1(float x, short& h, short& l) {
    union { float f; unsigned u; } v; v.f = x;
    h = (short)(v.u >> 16);
    union { float f; unsigned u; } rv; rv.f = v.f - bf2f(h);
    l = (short)(rv.u >> 16);
}

// async 16B/lane global->LDS; lds base must be wave-uniform (dest = base + lane*16)
__device__ inline void load_lds16(const void* g, void* l) {
    __builtin_amdgcn_global_load_lds(
        (const __attribute__((address_space(1))) void*)g,
        (__attribute__((address_space(3))) void*)l, 16, 0, 0);
}

// ---------------- CSR build ----------------

__global__ void hist_kernel(const int* __restrict__ dst, int* __restrict__ deg, int E) {
    int e = blockIdx.x * 256 + threadIdx.x;
    if (e < E) atomicAdd(&deg[dst[e]], 1);
}

__global__ void scan_block_kernel(const int* __restrict__ deg, int* __restrict__ offs,
                                  int* __restrict__ bsums, int n) {
    __shared__ int s[256];
    int tid = threadIdx.x;
    int i = blockIdx.x * 256 + tid;
    int v = (i < n) ? deg[i] : 0;
    s[tid] = v;
    __syncthreads();
    for (int off = 1; off < 256; off <<= 1) {
        int x = (tid >= off) ? s[tid - off] : 0;
        __syncthreads();
        s[tid] += x;
        __syncthreads();
    }
    if (i < n) offs[i] = s[tid] - v;
    if (tid == 255) bsums[blockIdx.x] = s[255];
}

__global__ void scan_sums_kernel(const int* __restrict__ bsums, int* __restrict__ boffs, int nb) {
    __shared__ int s[256];
    int tid = threadIdx.x;
    int v = (tid < nb) ? bsums[tid] : 0;
    s[tid] = v;
    __syncthreads();
    for (int off = 1; off < 256; off <<= 1) {
        int x = (tid >= off) ? s[tid - off] : 0;
        __syncthreads();
        s[tid] += x;
        __syncthreads();
    }
    boffs[tid] = s[tid] - v;
}

__global__ void add_offs_kernel(int* __restrict__ offs, const int* __restrict__ boffs,
                                int* __restrict__ cursor, int n, int total) {
    int i = blockIdx.x * 256 + threadIdx.x;
    if (i < n) {
        int o = offs[i] + boffs[blockIdx.x];
        offs[i] = o;
        cursor[i] = o;
    }
    if (i == 0) offs[n] = total;
}

__global__ void scatter_kernel(const int* __restrict__ src, const int* __restrict__ dst,
                               int* __restrict__ cursor, int* __restrict__ psrc, int E) {
    int e = blockIdx.x * 256 + threadIdx.x;
    if (e < E) {
        int p = atomicAdd(&cursor[dst[e]], 1);
        psrc[p] = src[e];
    }
}

// ---------------- A (row-major fp32) -> row-major bf16 hi/lo ----------------

__global__ __launch_bounds__(256) void splitA_rm(const float* __restrict__ A,
                                                 short* __restrict__ hi,
                                                 short* __restrict__ lo,
                                                 int total8) {
    int tid = blockIdx.x * 256 + threadIdx.x;
    if (tid >= total8) return;
    const float* p = A + (size_t)tid * 8;
    float4 x0 = ((const float4*)p)[0];
    float4 x1 = ((const float4*)p)[1];
    float xs[8] = {x0.x, x0.y, x0.z, x0.w, x1.x, x1.y, x1.z, x1.w};
    short8 hv, lv;
#pragma unroll
    for (int j = 0; j < 8; ++j) { short h, l; split1(xs[j], h, l); hv[j] = h; lv[j] = l; }
    ((short8*)hi)[tid] = hv;
    ((short8*)lo)[tid] = lv;
}

// ---------------- B -> hi/lo in MFMA B-fragment order ----------------
// offset (x8) = (c*(N/16)+g)*64 + lane ; lane=(n&15)+16*((k&31)>>3), j=k&7

__global__ __launch_bounds__(256) void splitB_kernel(const float* __restrict__ B,
                                                     short* __restrict__ hi,
                                                     short* __restrict__ lo,
                                                     int K, int N) {
    int tid = blockIdx.x * 256 + threadIdx.x;
    int NG = N >> 4;
    int total = (K >> 5) * NG * 64;
    if (tid >= total) return;
    int lane = tid & 63;
    int rc = tid >> 6;
    int g = rc % NG, c = rc / NG;
    int n = g * 16 + (lane & 15);
    int k = c * 32 + (lane >> 4) * 8;
    short8 hv, lv;
#pragma unroll
    for (int j = 0; j < 8; ++j) {
        float x = B[(size_t)(k + j) * N + n];
        short h = f2bf_rne(x);
        hv[j] = h;
        lv[j] = f2bf_rne(x - bf2f(h));
    }
    ((short8*)hi)[tid] = hv;
    ((short8*)lo)[tid] = lv;
}

// f16 hi/lo variant (for W1)
__global__ __launch_bounds__(256) void splitB_f16_kernel(const float* __restrict__ B,
                                                         _Float16* __restrict__ hi,
                                                         _Float16* __restrict__ lo,
                                                         int K, int N) {
    int tid = blockIdx.x * 256 + threadIdx.x;
    int NG = N >> 4;
    int total = (K >> 5) * NG * 64;
    if (tid >= total) return;
    int lane = tid & 63;
    int rc = tid >> 6;
    int g = rc % NG, c = rc / NG;
    int n = g * 16 + (lane & 15);
    int k = c * 32 + (lane >> 4) * 8;
    half8 hv, lv;
#pragma unroll
    for (int j = 0; j < 8; ++j) {
        float x = B[(size_t)(k + j) * N + n];
        _Float16 h = (_Float16)x;
        hv[j] = h;
        lv[j] = (_Float16)(x - (float)h);
    }
    ((half8*)hi)[tid] = hv;
    ((half8*)lo)[tid] = lv;
}

// permuted-W2 f16 HI ONLY: Bp[h*256+k, c] = W2[k, h*256+c]; K=1024, N=256
// (final GEMM output is head-mean: x0.25 scales W2-quant error to ~1.5e-4)
__global__ __launch_bounds__(256) void splitB2_f16s_kernel(const float* __restrict__ W2,
                                                           _Float16* __restrict__ hi) {
    int tid = blockIdx.x * 256 + threadIdx.x;
    const int NG = 16;
    int total = (1024 >> 5) * NG * 64;   // 32768
    if (tid >= total) return;
    int lane = tid & 63;
    int rc = tid >> 6;
    int g = rc % NG, c = rc / NG;
    int n = g * 16 + (lane & 15);
    int kk = c * 32 + (lane >> 4) * 8;
    half8 hv;
#pragma unroll
    for (int j = 0; j < 8; ++j) {
        int kg = kk + j;
        int h = kg >> 8, k = kg & 255;
        hv[j] = (_Float16)W2[(size_t)k * 1024 + h * 256 + n];
    }
    ((half8*)hi)[tid] = hv;
}

// ---------------- MFMA GEMMs, N=256, A via async LDS staging ----------------
// block: 64 rows x 256 cols; wave w owns rows [bm,bm+64) x cols [w*64,(w+1)*64).
// Fused elr epilogue (alv!=null): from fp32 acc, pre-quantization.

__device__ inline floatx4 mfma16(short8 a, short8 b, floatx4 c) {
    return __builtin_amdgcn_mfma_f32_16x16x32_bf16(a, b, c, 0, 0, 0);
}
__device__ inline floatx4 mfma16h(half8 a, half8 b, floatx4 c) {
    return __builtin_amdgcn_mfma_f32_16x16x32_f16(a, b, c, 0, 0, 0);
}

// bf16-pair A x bf16-pair B (3-MFMA). Used for layer 0 (A = fp32 feat split).
__global__ __launch_bounds__(256) void gemm_n256l(const short* __restrict__ Ahi,
                                                  const short* __restrict__ Alo,
                                                  const short* __restrict__ Bh,
                                                  const short* __restrict__ Bl,
                                                  _Float16* __restrict__ Cf,
                                                  const float* __restrict__ alv,
                                                  const float* __restrict__ arv,
                                                  float* __restrict__ elo,
                                                  float* __restrict__ ero,
                                                  int M, int K) {
    int KC = K >> 5;
    __shared__ short AhL[2048];   // 4 m-tiles x 64 lanes x 8 shorts = 4 KB
    __shared__ short AlL[2048];
    int t = threadIdx.x;
    int lane = t & 63;
    int w = t >> 6;
    int bm = blockIdx.x * 64;
    int g0 = w * 4;
    const short8* pBh = (const short8*)Bh;
    const short8* pBl = (const short8*)Bl;

    floatx4 acc[4][4] = {};

    int row = bm + (w << 4) + (lane & 15);
    if (row >= M) row = M - 1;                    // clamp: junk rows never stored
    const short* gh = Ahi + (size_t)row * K + ((lane >> 4) << 3);
    const short* gl = Alo + (size_t)row * K + ((lane >> 4) << 3);
    short* lh = AhL + w * 512;                    // wave-uniform LDS base
    short* ll = AlL + w * 512;

    for (int c = 0; c < KC; ++c) {
        load_lds16(gh + (size_t)c * 32, lh);
        load_lds16(gl + (size_t)c * 32, ll);
        short8 bh[4], bl[4];
#pragma unroll
        for (int g = 0; g < 4; ++g) {
            bh[g] = pBh[((size_t)c * 16 + g0 + g) * 64 + lane];
            bl[g] = pBl[((size_t)c * 16 + g0 + g) * 64 + lane];
        }
        __syncthreads();   // drains vmcnt: LDS staged, B regs ready
#pragma unroll
        for (int mt = 0; mt < 4; ++mt) {
            short8 ah = *(const short8*)(AhL + mt * 512 + lane * 8);
            short8 al = *(const short8*)(AlL + mt * 512 + lane * 8);
#pragma unroll
            for (int g = 0; g < 4; ++g) {
                acc[mt][g] = mfma16(ah, bh[g], acc[mt][g]);
                acc[mt][g] = mfma16(al, bh[g], acc[mt][g]);
                acc[mt][g] = mfma16(ah, bl[g], acc[mt][g]);
            }
        }
        __syncthreads();   // all LDS reads done before next overwrite
    }

    // C/D layout: col = lane&15, row = (lane>>4)*4 + reg
    int rowb = bm + (lane >> 4) * 4;
    int colb = w * 64 + (lane & 15);
#pragma unroll
    for (int mt = 0; mt < 4; ++mt) {
#pragma unroll
        for (int r = 0; r < 4; ++r) {
            int rr = rowb + mt * 16 + r;
            if (rr < M) {
#pragma unroll
                for (int g = 0; g < 4; ++g) {
                    Cf[(size_t)rr * 256 + colb + g * 16] = (_Float16)acc[mt][g][r];
                }
            }
        }
    }

    // fused elr: el[rr,w] = sum_f z[rr, w*64+f]*alv[w*64+f] (f = (lane&15)+g*16)
    if (alv) {
        float alr[4], arr_[4];
#pragma unroll
        for (int g = 0; g < 4; ++g) {
            int f = w * 64 + (lane & 15) + g * 16;
            alr[g] = alv[f];
            arr_[g] = arv[f];
        }
#pragma unroll
        for (int mt = 0; mt < 4; ++mt) {
#pragma unroll
            for (int r = 0; r < 4; ++r) {
                float se = acc[mt][0][r] * alr[0] + acc[mt][1][r] * alr[1] +
                           acc[mt][2][r] * alr[2] + acc[mt][3][r] * alr[3];
                float sr = acc[mt][0][r] * arr_[0] + acc[mt][1][r] * arr_[1] +
                           acc[mt][2][r] * arr_[2] + acc[mt][3][r] * arr_[3];
                se += __shfl_xor(se, 1); se += __shfl_xor(se, 2);
                se += __shfl_xor(se, 4); se += __shfl_xor(se, 8);
                sr += __shfl_xor(sr, 1); sr += __shfl_xor(sr, 2);
                sr += __shfl_xor(sr, 4); sr += __shfl_xor(sr, 8);
                int rr = rowb + mt * 16 + r;
                if ((lane & 15) == 0 && rr < M) {
                    elo[rr * 4 + w] = se;
                    ero[rr * 4 + w] = sr;
                }
            }
        }
    }
}

// single-f16 A x f16 B (pair if Bl!=null, else single). Used for L1
// (A=h0 f16, B pair) and final (A=aggregated h1 f16, K=1024, B single).
__global__ __launch_bounds__(256) void gemm_f16_n256(const _Float16* __restrict__ A,
                                                     const _Float16* __restrict__ Bh,
                                                     const _Float16* __restrict__ Bl,
                                                     const float* __restrict__ bias4,
                                                     float* __restrict__ C,
                                                     _Float16* __restrict__ Cf,
                                                     const float* __restrict__ alv,
                                                     const float* __restrict__ arv,
                                                     float* __restrict__ elo,
                                                     float* __restrict__ ero,
                                                     int M, int K) {
    int KC = K >> 5;
    __shared__ _Float16 AL[2048];   // 4 m-tiles x 64 lanes x 8 halves = 4 KB
    int t = threadIdx.x;
    int lane = t & 63;
    int w = t >> 6;
    int bm = blockIdx.x * 64;
    int g0 = w * 4;
    const half8* pBh = (const half8*)Bh;
    const half8* pBl = (const half8*)Bl;
    bool dual = (Bl != nullptr);

    floatx4 acc[4][4] = {};

    int row = bm + (w << 4) + (lane & 15);
    if (row >= M) row = M - 1;                    // clamp: junk rows never stored
    const _Float16* gA = A + (size_t)row * K + ((lane >> 4) << 3);
    _Float16* lA = AL + w * 512;                  // wave-uniform LDS base

    for (int c = 0; c < KC; ++c) {
        load_lds16(gA + (size_t)c * 32, lA);
        half8 bh[4], bl[4];
#pragma unroll
        for (int g = 0; g < 4; ++g) {
            bh[g] = pBh[((size_t)c * 16 + g0 + g) * 64 + lane];
        }
        if (dual) {
#pragma unroll
            for (int g = 0; g < 4; ++g) {
                bl[g] = pBl[((size_t)c * 16 + g0 + g) * 64 + lane];
            }
        }
        __syncthreads();   // drains vmcnt: LDS staged, B regs ready
#pragma unroll
        for (int mt = 0; mt < 4; ++mt) {
            half8 a = *(const half8*)(AL + mt * 512 + lane * 8);
#pragma unroll
            for (int g = 0; g < 4; ++g) {
                acc[mt][g] = mfma16h(a, bh[g], acc[mt][g]);
            }
            if (dual) {
#pragma unroll
                for (int g = 0; g < 4; ++g) {
                    acc[mt][g] = mfma16h(a, bl[g], acc[mt][g]);
                }
            }
        }
        __syncthreads();   // all LDS reads done before next overwrite
    }

    // C/D layout: col = lane&15, row = (lane>>4)*4 + reg
    int rowb = bm + (lane >> 4) * 4;
    int colb = w * 64 + (lane & 15);
#pragma unroll
    for (int mt = 0; mt < 4; ++mt) {
#pragma unroll
        for (int r = 0; r < 4; ++r) {
            int rr = rowb + mt * 16 + r;
            if (rr < M) {
#pragma unroll
                for (int g = 0; g < 4; ++g) {
                    int col = colb + g * 16;
                    float v = acc[mt][g][r];
                    if (bias4) {
                        v = 0.25f * (v + bias4[col] + bias4[col + 256] +
                                     bias4[col + 512] + bias4[col + 768]);
                    }
                    if (Cf) Cf[(size_t)rr * 256 + col] = (_Float16)v;
                    else    C[(size_t)rr * 256 + col] = v;
                }
            }
        }
    }

    // fused elr from fp32 acc
    if (alv) {
        float alr[4], arr_[4];
#pragma unroll
        for (int g = 0; g < 4; ++g) {
            int f = w * 64 + (lane & 15) + g * 16;
            alr[g] = alv[f];
            arr_[g] = arv[f];
        }
#pragma unroll
        for (int mt = 0; mt < 4; ++mt) {
#pragma unroll
            for (int r = 0; r < 4; ++r) {
                float se = acc[mt][0][r] * alr[0] + acc[mt][1][r] * alr[1] +
                           acc[mt][2][r] * alr[2] + acc[mt][3][r] * alr[3];
                float sr = acc[mt][0][r] * arr_[0] + acc[mt][1][r] * arr_[1] +
                           acc[mt][2][r] * arr_[2] + acc[mt][3][r] * arr_[3];
                se += __shfl_xor(se, 1); se += __shfl_xor(se, 2);
                se += __shfl_xor(se, 4); se += __shfl_xor(se, 8);
                sr += __shfl_xor(sr, 1); sr += __shfl_xor(sr, 2);
                sr += __shfl_xor(sr, 4); sr += __shfl_xor(sr, 8);
                int rr = rowb + mt * 16 + r;
                if ((lane & 15) == 0 && rr < M) {
                    elo[rr * 4 + w] = se;
                    ero[rr * 4 + w] = sr;
                }
            }
        }
    }
}

// ---------------- attention score parts (layer 2) ----------------

// val[h*256+k] = sum_j W2[k,h*256+j]*al2[h,j] ; var likewise with ar2
__global__ __launch_bounds__(256) void proj_av_kernel(const float* __restrict__ W2,
                                                      const float* __restrict__ al2,
                                                      const float* __restrict__ ar2,
                                                      float* __restrict__ val,
                                                      float* __restrict__ var_) {
    int gid = blockIdx.x * 256 + threadIdx.x;
    int w = gid >> 6;
    int lane = threadIdx.x & 63;
    if (w >= 1024) return;
    int h = w >> 8, k = w & 255;
    const float* wrow = W2 + (size_t)k * 1024 + h * 256;
    const float* ap = al2 + h * 256;
    const float* rp = ar2 + h * 256;
    float sv = 0.f, sr = 0.f;
    for (int j = lane; j < 256; j += 64) {
        float x = wrow[j];
        sv += x * ap[j];
        sr += x * rp[j];
    }
#pragma unroll
    for (int off = 32; off > 0; off >>= 1) {
        sv += __shfl_down(sv, off);
        sr += __shfl_down(sr, off);
    }
    if (lane == 0) { val[w] = sv; var_[w] = sr; }
}

// el[n,h] = h1[n,:]·val[h,:], er likewise (h1 fp16)
__global__ __launch_bounds__(256) void elr2_kernel(const _Float16* __restrict__ h1,
                                                   const float* __restrict__ val,
                                                   const float* __restrict__ var_,
                                                   float* __restrict__ el,
                                                   float* __restrict__ er) {
    int gid = blockIdx.x * 256 + threadIdx.x;
    int w = gid >> 6;
    int lane = threadIdx.x & 63;
    if (w >= NN * 4) return;
    int n = w >> 2, h = w & 3;
    const _Float16* hr = h1 + (size_t)n * 256;
    const float* vp = val + h * 256;
    const float* rp = var_ + h * 256;
    float se = 0.f, sr = 0.f;
    for (int k = lane; k < 256; k += 64) {
        float x = (float)hr[k];
        se += x * vp[k];
        sr += x * rp[k];
    }
#pragma unroll
    for (int off = 32; off > 0; off >>= 1) {
        se += __shfl_down(se, off);
        sr += __shfl_down(sr, off);
    }
    if (lane == 0) { el[w] = se; er[w] = sr; }
}

// ---------------- aggregation: 1-wave blocks, half4 loads ----------------
// Block = 64 lanes = one node. Lane l owns cols 4l..4l+3 (head h = l>>4).
// p-phase: chunk = 16 edges x 4 heads = 64 lanes (e_local = l>>2, hh = l&3);
// den via shfl_xor strides {4,8,16,32} (preserves hh groups), lanes 0..3
// accumulate den_lds across chunks (single wave: program order, no atomics).
// Gather: one half4 (8B) load per edge per lane = 512B/wave (full row).

// z-gather (layers 0 & 1): elu epilogue, f16 out [N,256].
__global__ __launch_bounds__(64) void agg_z64_kernel(const _Float16* __restrict__ z,
                                                     const float* __restrict__ el,
                                                     const float* __restrict__ er,
                                                     const int* __restrict__ offs,
                                                     const int* __restrict__ psrc,
                                                     const float* __restrict__ bias,
                                                     _Float16* __restrict__ out) {
    int n = blockIdx.x;
    int l = threadIdx.x;
    __shared__ float p_lds[16][4];
    __shared__ int src_lds[16];
    __shared__ float den_lds[4];
    if (l < 4) den_lds[l] = 0.f;
    int e_local = l >> 2, hh = l & 3;
    int h = l >> 4;
    float er_n = er[n * 4 + hh];
    int beg = offs[n], end = offs[n + 1];
    float a0 = 0.f, a1 = 0.f, a2 = 0.f, a3 = 0.f;
    for (int base = beg; base < end; base += 16) {
        int cnt = min(16, end - base);
        __syncthreads();
        float p = 0.f;
        if (e_local < cnt) {
            int s = psrc[base + e_local];
            if (hh == 0) src_lds[e_local] = s;
            float sc = el[s * 4 + hh] + er_n;
            sc = (sc > 0.f) ? sc : 0.2f * sc;
            p = __expf(sc);
            p_lds[e_local][hh] = p;
        }
        float d = p;
        d += __shfl_xor(d, 4);  d += __shfl_xor(d, 8);
        d += __shfl_xor(d, 16); d += __shfl_xor(d, 32);
        if (l < 4) den_lds[l] += d;
        __syncthreads();
        for (int e = 0; e < cnt; ++e) {
            half4 v = *(const half4*)(z + (size_t)src_lds[e] * 256 + (l << 2));
            float pe = p_lds[e][h];
            a0 += pe * (float)v[0];
            a1 += pe * (float)v[1];
            a2 += pe * (float)v[2];
            a3 += pe * (float)v[3];
        }
    }
    __syncthreads();
    float rd = 1.f / fmaxf(den_lds[h], 1e-9f);
    float vals[4] = {a0, a1, a2, a3};
    half4 o;
#pragma unroll
    for (int j = 0; j < 4; ++j) {
        float x = vals[j] * rd + bias[(l << 2) + j];
        x = (x > 0.f) ? x : (__expf(x) - 1.f);
        o[j] = (_Float16)x;
    }
    *(half4*)(out + (size_t)n * 256 + (l << 2)) = o;
}

// layer-2 aggregation of h1 (fp16) -> single f16 [N,1024] (all 4 heads/lane).
__global__ __launch_bounds__(64) void aggH_64_kernel(const _Float16* __restrict__ h1,
                                                     const float* __restrict__ el,
                                                     const float* __restrict__ er,
                                                     const int* __restrict__ offs,
                                                     const int* __restrict__ psrc,
                                                     _Float16* __restrict__ oA) {
    int n = blockIdx.x;
    int l = threadIdx.x;
    __shared__ __align__(16) float p_lds[16][4];
    __shared__ int src_lds[16];
    __shared__ float den_lds[4];
    if (l < 4) den_lds[l] = 0.f;
    int e_local = l >> 2, hh = l & 3;
    float er_n = er[n * 4 + hh];
    int beg = offs[n], end = offs[n + 1];
    float acc[4][4] = {};   // [head][colj]
    for (int base = beg; base < end; base += 16) {
        int cnt = min(16, end - base);
        __syncthreads();
        float p = 0.f;
        if (e_local < cnt) {
            int s = psrc[base + e_local];
            if (hh == 0) src_lds[e_local] = s;
            float sc = el[s * 4 + hh] + er_n;
            sc = (sc > 0.f) ? sc : 0.2f * sc;
            p = __expf(sc);
            p_lds[e_local][hh] = p;
        }
        float d = p;
        d += __shfl_xor(d, 4);  d += __shfl_xor(d, 8);
        d += __shfl_xor(d, 16); d += __shfl_xor(d, 32);
        if (l < 4) den_lds[l] += d;
        __syncthreads();
        for (int e = 0; e < cnt; ++e) {
            half4 v = *(const half4*)(h1 + (size_t)src_lds[e] * 256 + (l << 2));
            float vf0 = (float)v[0], vf1 = (float)v[1];
            float vf2 = (float)v[2], vf3 = (float)v[3];
            floatx4 pv = *(const floatx4*)&p_lds[e][0];
#pragma unroll
            for (int hd = 0; hd < 4; ++hd) {
                acc[hd][0] += pv[hd] * vf0;
                acc[hd][1] += pv[hd] * vf1;
                acc[hd][2] += pv[hd] * vf2;
                acc[hd][3] += pv[hd] * vf3;
            }
        }
    }
    __syncthreads();
    size_t base_o = (size_t)n * 1024 + (l << 2);
#pragma unroll
    for (int hd = 0; hd < 4; ++hd) {
        float rd = 1.f / fmaxf(den_lds[hd], 1e-9f);
        half4 o;
#pragma unroll
        for (int j = 0; j < 4; ++j) o[j] = (_Float16)(acc[hd][j] * rd);
        *(half4*)(oA + base_o + hd * 256) = o;
    }
}

// ---------------- launch ----------------

extern "C" void kernel_launch(void* const* d_in, const int* in_sizes, int n_in,
                              void* d_out, int out_size, void* d_ws, size_t ws_size,
                              hipStream_t stream) {
    const float* feat = (const float*)d_in[0];
    const float* W0 = (const float*)d_in[1];
    const float* al0 = (const float*)d_in[2];
    const float* ar0 = (const float*)d_in[3];
    const float* b0 = (const float*)d_in[4];
    const float* W1 = (const float*)d_in[5];
    const float* al1 = (const float*)d_in[6];
    const float* ar1 = (const float*)d_in[7];
    const float* b1 = (const float*)d_in[8];
    const float* W2 = (const float*)d_in[9];
    const float* al2 = (const float*)d_in[10];
    const float* ar2 = (const float*)d_in[11];
    const float* b2 = (const float*)d_in[12];
    const int* src = (const int*)d_in[13];
    const int* dst = (const int*)d_in[14];
    float* out = (float*)d_out;

    // ---- workspace layout (~262.5 MB), time-multiplexed big slots ----
    float* slotA = (float*)d_ws;
    _Float16* zh = (_Float16*)slotA;                      // [N,256] fp16 (z slot)
    short* feathi = (short*)(slotA + (size_t)NN * 256);   // 50000*128 shorts
    short* featlo = feathi + (size_t)NN * 128;
    _Float16* Af16 = (_Float16*)slotA;                    // [N,1024] f16 (layer 2)
    float* slotB = slotA + (size_t)NN * 1024;
    _Float16* h0f = (_Float16*)slotB;                     // [N,256] f16
    _Float16* h1h = (_Float16*)slotB;                     // [N,256] f16 (layer 2)
    float* el = slotB + (size_t)NN * 256;                 // 200000
    float* er = el + (size_t)NN * NH_HEADS;               // 200000
    int* deg = (int*)(er + (size_t)NN * NH_HEADS);        // 50000
    int* offs = deg + NN;                                 // 50001 (+1 pad)
    int* cursor = offs + NN + 2;                          // 50000
    int* bsums = cursor + NN;                             // 256
    int* boffs = bsums + 256;                             // 256
    int* psrc = boffs + 256;                              // 800000 (+2 pad)
    short* Bh = (short*)(psrc + NE + 2);                  // 262144 shorts / half8s
    short* Bl = Bh + 262144;                              // 262144 shorts
    float* val = (float*)(Bl + 262144);                   // 1024
    float* var_ = val + 1024;                             // 1024

    // ---- CSR build (by dst) ----
    hipMemsetAsync(deg, 0, NN * sizeof(int), stream);
    hist_kernel<<<(NE + 255) / 256, 256, 0, stream>>>(dst, deg, NE);
    int nb = (NN + 255) / 256;
    scan_block_kernel<<<nb, 256, 0, stream>>>(deg, offs, bsums, NN);
    scan_sums_kernel<<<1, 256, 0, stream>>>(bsums, boffs, nb);
    add_offs_kernel<<<nb, 256, 0, stream>>>(offs, boffs, cursor, NN, NE);
    scatter_kernel<<<(NE + 255) / 256, 256, 0, stream>>>(src, dst, cursor, psrc, NE);

    int mb64 = (NN + 63) / 64; // 782

    // ---- layer 0: 128 -> 4x64, elu (bf16-pair GEMM, elr fused; z fp16) ----
    splitA_rm<<<(NN * 128 / 8 + 255) / 256, 256, 0, stream>>>(feat, feathi, featlo, NN * 128 / 8);
    splitB_kernel<<<(4096 + 255) / 256, 256, 0, stream>>>(W0, Bh, Bl, 128, 256);
    gemm_n256l<<<mb64, 256, 0, stream>>>(feathi, featlo, Bh, Bl, zh,
                                         al0, ar0, el, er, NN, 128);
    agg_z64_kernel<<<NN, 64, 0, stream>>>(zh, el, er, offs, psrc, b0, h0f);

    // ---- layer 1: 256 -> 4x64, elu (f16 GEMM: A=h0 single f16, B pair) ----
    splitB_f16_kernel<<<(8192 + 255) / 256, 256, 0, stream>>>(W1, (_Float16*)Bh,
                                                              (_Float16*)Bl, 256, 256);
    gemm_f16_n256<<<mb64, 256, 0, stream>>>(h0f, (const _Float16*)Bh, (const _Float16*)Bl,
                                            nullptr, nullptr, zh, al1, ar1, el, er,
                                            NN, 256);
    agg_z64_kernel<<<NN, 64, 0, stream>>>(zh, el, er, offs, psrc, b1, h1h);

    // ---- layer 2: score from aggregated h1, then f16 K=1024 projection ----
    proj_av_kernel<<<256, 256, 0, stream>>>(W2, al2, ar2, val, var_);
    elr2_kernel<<<NN, 256, 0, stream>>>(h1h, val, var_, el, er);
    aggH_64_kernel<<<NN, 64, 0, stream>>>(h1h, el, er, offs, psrc, Af16);
    splitB2_f16s_kernel<<<(32768 + 255) / 256, 256, 0, stream>>>(W2, (_Float16*)Bh);
    gemm_f16_n256<<<mb64, 256, 0, stream>>>(Af16, (const _Float16*)Bh, nullptr,
                                            b2, out, nullptr, nullptr, nullptr,
                                            nullptr, nullptr, NN, 1024);
}